// Round 3
// baseline (24968.076 us; speedup 1.0000x reference)
//
#include <hip/hip_runtime.h>
#include <math.h>

#define NE 320000
#define NNODES 10000
#define EB 16
#define NBLK (NE / EB)

__device__ __forceinline__ float silu(float x) { return x / (1.0f + __expf(-x)); }
__device__ __forceinline__ float cutf(float len) {
    float x = len * (1.0f / 6.0f);
    float x2 = x * x, x6 = x2 * x2 * x2;
    float f = 1.0f - 28.0f * x6 + 48.0f * x6 * x - 21.0f * x6 * x2;
    return (x < 1.0f) ? f : 0.0f;
}

// ---------------------------------------------------------------- zero
__global__ __launch_bounds__(256) void k_zero(float* __restrict__ p, int n) {
    int i = blockIdx.x * 256 + threadIdx.x;
    if (i < n) p[i] = 0.f;
}

// ---------------------------------------------------------------- recompute latents0 into Q (P = scratch for h1)
__device__ __forceinline__ void compute_lat0(
    const float* nodeinv, const float* edgeinv, const float* elen,
    const int* eidx, const float* W2a, const float* W2b,
    int e0, int t, float (*P)[256], float (*Q)[256], float (*M)[140],
    float* s_cut) {
    if (t < EB) s_cut[t] = cutf(elen[e0 + t]);
    for (int i = t; i < EB * 136; i += 256) {
        int ee = i / 136, k = i - ee * 136;
        int e = e0 + ee;
        float v;
        if (k < 64)       v = nodeinv[eidx[e] * 64 + k];
        else if (k < 128) v = nodeinv[eidx[NE + e] * 64 + (k - 64)];
        else              v = edgeinv[(size_t)e * 8 + (k - 128)];
        M[ee][k] = v;
    }
    __syncthreads();
    float acc[EB];
#pragma unroll
    for (int ee = 0; ee < EB; ++ee) acc[ee] = 0.f;
    for (int k = 0; k < 136; ++k) {
        float w = W2a[k * 256 + t];
#pragma unroll
        for (int ee = 0; ee < EB; ++ee) acc[ee] = fmaf(M[ee][k], w, acc[ee]);
    }
#pragma unroll
    for (int ee = 0; ee < EB; ++ee) P[ee][t] = silu(acc[ee]);
    __syncthreads();
#pragma unroll
    for (int ee = 0; ee < EB; ++ee) acc[ee] = 0.f;
    for (int k = 0; k < 256; ++k) {
        float w = W2b[k * 256 + t];
#pragma unroll
        for (int ee = 0; ee < EB; ++ee) acc[ee] = fmaf(P[ee][k], w, acc[ee]);
    }
#pragma unroll
    for (int ee = 0; ee < EB; ++ee) Q[ee][t] = s_cut[ee] * silu(acc[ee]);
    __syncthreads();
}

// ---------------------------------------------------------------- K1: latents0 + (lat0@Wenv0[:,96:192]) + scatter -> env
__global__ __launch_bounds__(256) void k1_lat_scatter0(
    const float* __restrict__ nodeinv, const float* __restrict__ edgeinv,
    const float* __restrict__ elen, const float* __restrict__ edge_attr,
    const int* __restrict__ eidx, const float* __restrict__ W2a,
    const float* __restrict__ W2b, const float* __restrict__ Wenv0,
    float* __restrict__ env) {
    __shared__ float P[EB][256], Q[EB][256], M[EB][140];
    __shared__ float s_cut[EB];
    int t = threadIdx.x;
    int e0 = blockIdx.x * EB;
    compute_lat0(nodeinv, edgeinv, elen, eidx, W2a, W2b, e0, t, P, Q, M, s_cut);
    if (t < 192) {
        int col = t % 96, half = t / 96;
        float a[8];
#pragma unroll
        for (int i = 0; i < 8; ++i) a[i] = 0.f;
        for (int k = 0; k < 256; ++k) {
            float w = Wenv0[k * 192 + 96 + col];
#pragma unroll
            for (int i = 0; i < 8; ++i) a[i] = fmaf(Q[half * 8 + i][k], w, a[i]);
        }
#pragma unroll
        for (int i = 0; i < 8; ++i) M[half * 8 + i][col] = a[i];
    }
    __syncthreads();
    for (int i = t; i < EB * 32; i += 256) {
        int el = i >> 5, k = i & 31;
        int e = e0 + el;
        float cw = s_cut[el];
        int n = eidx[e];
        float w0 = M[el][k * 3 + 0] * cw;
        float w1 = M[el][k * 3 + 1] * cw;
        float w2 = M[el][k * 3 + 2] * cw;
        float* dst = env + (size_t)n * 288 + k;
#pragma unroll
        for (int m = 0; m < 9; ++m) {
            float w = (m == 0) ? w0 : ((m < 4) ? w1 : w2);
            atomicAdd(dst + m * 32, edge_attr[(size_t)e * 9 + m] * w);
        }
    }
}

// ---------------------------------------------------------------- node transform (mix -> prod -> mix), env layout (N, 9, 32)
__global__ __launch_bounds__(288) void k_node(
    const float* envin, const float* __restrict__ nodeinv,
    const float* __restrict__ Wenvlin, const float* __restrict__ Wprod,
    const float* __restrict__ Wfeat, float* featOut) {
    __shared__ float s_env[288];
    __shared__ float s_inv[64];
    __shared__ float s_mix[288];
    __shared__ float s_ew[96];
    int n = blockIdx.x;
    int t = threadIdx.x;
    s_env[t] = envin[(size_t)n * 288 + t] * (1.0f / 32.0f);
    if (t < 64) s_inv[t] = nodeinv[n * 64 + t];
    __syncthreads();
    int m = t >> 5, j = t & 31;
    int l = (m == 0) ? 0 : ((m < 4) ? 1 : 2);
    float a = 0.f;
    for (int k = 0; k < 32; ++k) a = fmaf(s_env[m * 32 + k], Wenvlin[l * 1024 + k * 32 + j], a);
    if (t < 96) {
        int c = t >> 5, jj = t & 31;
        float b = 0.f;
        for (int tt = 0; tt < 64; ++tt) b = fmaf(s_inv[tt], Wprod[c * 2048 + tt * 32 + jj], b);
        s_ew[t] = b;
    }
    s_mix[t] = a;
    __syncthreads();
    float s = s_mix[j];
    float p = s_mix[t] * (s_ew[j] + s_ew[32 + j] * s + s_ew[64 + j] * s * s);
    __syncthreads();
    s_env[t] = p;
    __syncthreads();
    float o = 0.f;
    for (int jl = 0; jl < 32; ++jl) o = fmaf(s_env[m * 32 + jl], Wfeat[l * 1024 + jl * 32 + j], o);
    featOut[(size_t)n * 288 + t] = o;
}

// ---------------------------------------------------------------- K3: latents0 -> latents1 -> (lat1@Wenv1) + scatter -> env
__global__ __launch_bounds__(256) void k3_update_scatter1(
    const float* __restrict__ nodeinv, const float* __restrict__ edgeinv,
    const float* __restrict__ elen, const float* __restrict__ edge_attr,
    const int* __restrict__ eidx, const float* __restrict__ W2a,
    const float* __restrict__ W2b, const float* __restrict__ Wl1a,
    const float* __restrict__ Wl1b, const float* __restrict__ Wenv1,
    const float* __restrict__ featN0, float* __restrict__ env) {
    __shared__ float P[EB][256], Q[EB][256], M[EB][140];
    __shared__ float s_cut[EB];
    int t = threadIdx.x;
    int e0 = blockIdx.x * EB;
    compute_lat0(nodeinv, edgeinv, elen, eidx, W2a, W2b, e0, t, P, Q, M, s_cut);
    // l_norms of featN0[center] into M[.][0..95]
    for (int i = t; i < EB * 96; i += 256) {
        int ee = i / 96, rem = i - ee * 96;
        int l = rem >> 5, kk = rem & 31;
        int off = (l == 0) ? 0 : ((l == 1) ? 1 : 4);
        int d = (l == 0) ? 1 : ((l == 1) ? 3 : 5);
        const float* f = featN0 + (size_t)eidx[e0 + ee] * 288 + kk;
        float s = 1e-8f;
        for (int mm = off; mm < off + d; ++mm) { float x = f[mm * 32]; s = fmaf(x, x, s); }
        M[ee][rem] = sqrtf(s);
    }
    __syncthreads();
    float acc[EB];
#pragma unroll
    for (int ee = 0; ee < EB; ++ee) acc[ee] = 0.f;
    for (int k = 0; k < 256; ++k) {
        float w = Wl1a[k * 256 + t];
#pragma unroll
        for (int ee = 0; ee < EB; ++ee) acc[ee] = fmaf(Q[ee][k], w, acc[ee]);
    }
    for (int k = 0; k < 96; ++k) {
        float w = Wl1a[(256 + k) * 256 + t];
#pragma unroll
        for (int ee = 0; ee < EB; ++ee) acc[ee] = fmaf(M[ee][k], w, acc[ee]);
    }
#pragma unroll
    for (int ee = 0; ee < EB; ++ee) P[ee][t] = silu(acc[ee]);
    __syncthreads();
#pragma unroll
    for (int ee = 0; ee < EB; ++ee) acc[ee] = 0.f;
    for (int k = 0; k < 256; ++k) {
        float w = Wl1b[k * 256 + t];
#pragma unroll
        for (int ee = 0; ee < EB; ++ee) acc[ee] = fmaf(P[ee][k], w, acc[ee]);
    }
#pragma unroll
    for (int ee = 0; ee < EB; ++ee)
        Q[ee][t] = 0.8944271909999159f * Q[ee][t] +
                   0.4472135954999579f * s_cut[ee] * silu(acc[ee]);
    __syncthreads();
    if (t < 192) {
        int col = t % 96, half = t / 96;
        float a[8];
#pragma unroll
        for (int i = 0; i < 8; ++i) a[i] = 0.f;
        for (int k = 0; k < 256; ++k) {
            float w = Wenv1[k * 96 + col];
#pragma unroll
            for (int i = 0; i < 8; ++i) a[i] = fmaf(Q[half * 8 + i][k], w, a[i]);
        }
#pragma unroll
        for (int i = 0; i < 8; ++i) M[half * 8 + i][col] = a[i];
    }
    __syncthreads();
    for (int i = t; i < EB * 32; i += 256) {
        int el = i >> 5, k = i & 31;
        int e = e0 + el;
        float cw = s_cut[el];
        int n = eidx[e];
        float w0 = M[el][k * 3 + 0] * cw;
        float w1 = M[el][k * 3 + 1] * cw;
        float w2 = M[el][k * 3 + 2] * cw;
        float* dst = env + (size_t)n * 288 + k;
#pragma unroll
        for (int m = 0; m < 9; ++m) {
            float w = (m == 0) ? w0 : ((m < 4) ? w1 : w2);
            atomicAdd(dst + m * 32, edge_attr[(size_t)e * 9 + m] * w);
        }
    }
}

// ---------------------------------------------------------------- K5: recompute lat0->w0, lat1; S; Wfinlat contraction; readout
__global__ __launch_bounds__(256) void k5_final(
    const float* __restrict__ nodeinv, const float* __restrict__ edgeinv,
    const float* __restrict__ elen, const float* __restrict__ edge_attr,
    const int* __restrict__ eidx, const float* __restrict__ W2a,
    const float* __restrict__ W2b, const float* __restrict__ Wenv0,
    const float* __restrict__ Wl1a, const float* __restrict__ Wl1b,
    const float* __restrict__ Wfinlat, const float* __restrict__ Wro1,
    const float* __restrict__ Wro2, const float* __restrict__ featN0,
    const float* __restrict__ featN1, float* __restrict__ out) {
    __shared__ float P[EB][256], Q[EB][256], M[EB][140];
    __shared__ float s_w0[EB][96], s_S[EB][96], s_scal[EB][96];
    __shared__ float s_red[4][8][EB + 1];
    __shared__ float s_out[EB][9];
    __shared__ float s_cut[EB];
    int t = threadIdx.x;
    int e0 = blockIdx.x * EB;
    compute_lat0(nodeinv, edgeinv, elen, eidx, W2a, W2b, e0, t, P, Q, M, s_cut);
    // w0 = lat0 @ Wenv0[:, 0:96] -> s_w0 ; l_norms -> M (independent)
    if (t < 192) {
        int col = t % 96, half = t / 96;
        float a[8];
#pragma unroll
        for (int i = 0; i < 8; ++i) a[i] = 0.f;
        for (int k = 0; k < 256; ++k) {
            float w = Wenv0[k * 192 + col];
#pragma unroll
            for (int i = 0; i < 8; ++i) a[i] = fmaf(Q[half * 8 + i][k], w, a[i]);
        }
#pragma unroll
        for (int i = 0; i < 8; ++i) s_w0[half * 8 + i][col] = a[i];
    }
    for (int i = t; i < EB * 96; i += 256) {
        int ee = i / 96, rem = i - ee * 96;
        int l = rem >> 5, kk = rem & 31;
        int off = (l == 0) ? 0 : ((l == 1) ? 1 : 4);
        int d = (l == 0) ? 1 : ((l == 1) ? 3 : 5);
        const float* f = featN0 + (size_t)eidx[e0 + ee] * 288 + kk;
        float s = 1e-8f;
        for (int mm = off; mm < off + d; ++mm) { float x = f[mm * 32]; s = fmaf(x, x, s); }
        M[ee][rem] = sqrtf(s);
    }
    __syncthreads();
    float acc[EB];
#pragma unroll
    for (int ee = 0; ee < EB; ++ee) acc[ee] = 0.f;
    for (int k = 0; k < 256; ++k) {
        float w = Wl1a[k * 256 + t];
#pragma unroll
        for (int ee = 0; ee < EB; ++ee) acc[ee] = fmaf(Q[ee][k], w, acc[ee]);
    }
    for (int k = 0; k < 96; ++k) {
        float w = Wl1a[(256 + k) * 256 + t];
#pragma unroll
        for (int ee = 0; ee < EB; ++ee) acc[ee] = fmaf(M[ee][k], w, acc[ee]);
    }
#pragma unroll
    for (int ee = 0; ee < EB; ++ee) P[ee][t] = silu(acc[ee]);
    __syncthreads();
#pragma unroll
    for (int ee = 0; ee < EB; ++ee) acc[ee] = 0.f;
    for (int k = 0; k < 256; ++k) {
        float w = Wl1b[k * 256 + t];
#pragma unroll
        for (int ee = 0; ee < EB; ++ee) acc[ee] = fmaf(P[ee][k], w, acc[ee]);
    }
#pragma unroll
    for (int ee = 0; ee < EB; ++ee)
        Q[ee][t] = 0.8944271909999159f * Q[ee][t] +
                   0.4472135954999579f * s_cut[ee] * silu(acc[ee]);
    // S[e,l,k] = sum_m featN1[center,m,k]*sh[e,m]
    for (int i = t; i < EB * 96; i += 256) {
        int ee = i / 96, rem = i - ee * 96;
        int l = rem >> 5, kk = rem & 31;
        int off = (l == 0) ? 0 : ((l == 1) ? 1 : 4);
        int d = (l == 0) ? 1 : ((l == 1) ? 3 : 5);
        int e = e0 + ee;
        const float* f = featN1 + (size_t)eidx[e] * 288 + kk;
        float s = 0.f;
        for (int mm = off; mm < off + d; ++mm)
            s = fmaf(f[mm * 32], edge_attr[(size_t)e * 9 + mm], s);
        s_S[ee][rem] = s;
    }
    __syncthreads();
    // 12 tiles of the Wfinlat contraction
    int k = t >> 3, jj = t & 7;
    int wave = t >> 6, lane = t & 63;
    for (int tile = 0; tile < 12; ++tile) {
        int l = tile >> 2, jt = tile & 3;
        int j = jt * 8 + jj;
        int col = l * 1024 + k * 32 + j;
        float a[EB];
#pragma unroll
        for (int ee = 0; ee < EB; ++ee) a[ee] = 0.f;
        for (int c = 0; c < 256; ++c) {
            float w = Wfinlat[(size_t)c * 3072 + col];
#pragma unroll
            for (int ee = 0; ee < EB; ++ee) a[ee] = fmaf(Q[ee][c], w, a[ee]);
        }
#pragma unroll
        for (int ee = 0; ee < EB; ++ee) {
            float v = a[ee] * s_S[ee][l * 32 + k];
            v += __shfl_xor(v, 8);
            v += __shfl_xor(v, 16);
            v += __shfl_xor(v, 32);
            if (lane < 8) s_red[wave][lane][ee] = v;
        }
        __syncthreads();
        if (t < 128) {
            int ee = t >> 3, jjf = t & 7;
            int jo = jt * 8 + jjf;
            float tot = s_red[0][jjf][ee] + s_red[1][jjf][ee] +
                        s_red[2][jjf][ee] + s_red[3][jjf][ee];
            s_scal[ee][l * 32 + jo] = s_w0[ee][jo * 3 + l] * tot;
        }
        __syncthreads();
    }
    // readout
    float r[EB];
#pragma unroll
    for (int ee = 0; ee < EB; ++ee) r[ee] = 0.f;
    for (int kk = 0; kk < 256; ++kk) {
        float w = Wro1[kk * 256 + t];
#pragma unroll
        for (int ee = 0; ee < EB; ++ee) r[ee] = fmaf(Q[ee][kk], w, r[ee]);
    }
    for (int kk = 0; kk < 96; ++kk) {
        float w = Wro1[(256 + kk) * 256 + t];
#pragma unroll
        for (int ee = 0; ee < EB; ++ee) r[ee] = fmaf(s_scal[ee][kk], w, r[ee]);
    }
    float w2 = Wro2[t];
#pragma unroll
    for (int ee = 0; ee < EB; ++ee) P[ee][t] = silu(r[ee]) * w2;
    __syncthreads();
    if (t < 128) {
        int ee = t >> 3, part = t & 7;
        float s = 0.f;
        for (int c2 = 0; c2 < 32; ++c2) s += P[ee][part * 32 + ((c2 + ee) & 31)];
        s_out[ee][part] = s;
    }
    __syncthreads();
    if (t < EB) {
        float tot = 0.f;
#pragma unroll
        for (int p = 0; p < 8; ++p) tot += s_out[t][p];
        out[e0 + t] = tot;
    }
}

// ----------------------------------------------------------------
extern "C" void kernel_launch(void* const* d_in, const int* in_sizes, int n_in,
                              void* d_out, int out_size, void* d_ws, size_t ws_size,
                              hipStream_t stream) {
    (void)in_sizes; (void)n_in; (void)out_size;
    const float* edge_attr = (const float*)d_in[0];
    const float* edge_len  = (const float*)d_in[1];
    const float* edge_inv  = (const float*)d_in[2];
    const float* node_inv  = (const float*)d_in[3];
    const float* W2a     = (const float*)d_in[4];
    const float* W2b     = (const float*)d_in[5];
    const float* Wl1a    = (const float*)d_in[6];
    const float* Wl1b    = (const float*)d_in[7];
    const float* Wenv0   = (const float*)d_in[8];
    const float* Wenv1   = (const float*)d_in[9];
    const float* Wenvlin = (const float*)d_in[10];
    const float* Wprod   = (const float*)d_in[11];
    const float* Wfeat   = (const float*)d_in[12];
    const float* Wfinlat = (const float*)d_in[13];
    const float* Wro1    = (const float*)d_in[14];
    const float* Wro2    = (const float*)d_in[15];
    const int* eidx      = (const int*)d_in[16];
    float* out = (float*)d_out;

    // workspace: env + featN0, per-NODE only: 2 * 10000 * 288 * 4 = 23.04 MB
    size_t need = (size_t)2 * NNODES * 288 * sizeof(float);
    if (ws_size < need) return;  // if this trips: absmax == 0.318 again -> ws < 23MB
    float* env    = (float*)d_ws;              // bufA: env0 -> env1 -> featN1 (in-place)
    float* featN0 = env + (size_t)NNODES * 288;  // bufB

    const int ENV_N = NNODES * 288;
    k_zero<<<(ENV_N + 255) / 256, 256, 0, stream>>>(env, ENV_N);
    k1_lat_scatter0<<<NBLK, 256, 0, stream>>>(node_inv, edge_inv, edge_len, edge_attr,
                                              eidx, W2a, W2b, Wenv0, env);
    k_node<<<NNODES, 288, 0, stream>>>(env, node_inv, Wenvlin, Wprod, Wfeat, featN0);
    k_zero<<<(ENV_N + 255) / 256, 256, 0, stream>>>(env, ENV_N);
    k3_update_scatter1<<<NBLK, 256, 0, stream>>>(node_inv, edge_inv, edge_len, edge_attr,
                                                 eidx, W2a, W2b, Wl1a, Wl1b, Wenv1,
                                                 featN0, env);
    k_node<<<NNODES, 288, 0, stream>>>(env, node_inv, Wenvlin + 3072, Wprod + 6144,
                                       Wfeat + 3072, env);  // in-place: env1 -> featN1
    k5_final<<<NBLK, 256, 0, stream>>>(node_inv, edge_inv, edge_len, edge_attr, eidx,
                                       W2a, W2b, Wenv0, Wl1a, Wl1b, Wfinlat, Wro1, Wro2,
                                       featN0, env, out);
}

// Round 4
// 17980.670 us; speedup vs baseline: 1.3886x; 1.3886x over previous
//
#include <hip/hip_runtime.h>
#include <math.h>

#define NE 320000
#define NNODES 10000
#define EB 16
#define NBLK (NE / EB)

typedef _Float16 f16x8 __attribute__((ext_vector_type(8)));
typedef float f32x4 __attribute__((ext_vector_type(4)));

__device__ __forceinline__ float silu(float x) { return x / (1.0f + __expf(-x)); }
__device__ __forceinline__ float cutf(float len) {
    float x = len * (1.0f / 6.0f);
    float x2 = x * x, x6 = x2 * x2 * x2;
    float f = 1.0f - 28.0f * x6 + 48.0f * x6 * x - 21.0f * x6 * x2;
    return (x < 1.0f) ? f : 0.0f;
}

// ---------------------------------------------------------------- zero
__global__ __launch_bounds__(256) void k_zero(float* __restrict__ p, int n) {
    int i = blockIdx.x * 256 + threadIdx.x;
    if (i < n) p[i] = 0.f;
}

// ---------------------------------------------------------------- Wfinlat (256x3072 f32) -> WfinT (3072x256 f16)
__global__ __launch_bounds__(256) void k_wfin(const float* __restrict__ Wfinlat,
                                              _Float16* __restrict__ WfinT) {
    int col = blockIdx.x, c = threadIdx.x;
    WfinT[(size_t)col * 256 + c] = (_Float16)Wfinlat[(size_t)c * 3072 + col];
}

// ---------------------------------------------------------------- recompute latents0 into Q (P = scratch for h1)
__device__ __forceinline__ void compute_lat0(
    const float* nodeinv, const float* edgeinv, const float* elen,
    const int* eidx, const float* W2a, const float* W2b,
    int e0, int t, float (*P)[256], float (*Q)[256], float (*M)[140],
    float* s_cut) {
    if (t < EB) s_cut[t] = cutf(elen[e0 + t]);
    for (int i = t; i < EB * 136; i += 256) {
        int ee = i / 136, k = i - ee * 136;
        int e = e0 + ee;
        float v;
        if (k < 64)       v = nodeinv[eidx[e] * 64 + k];
        else if (k < 128) v = nodeinv[eidx[NE + e] * 64 + (k - 64)];
        else              v = edgeinv[(size_t)e * 8 + (k - 128)];
        M[ee][k] = v;
    }
    __syncthreads();
    float acc[EB];
#pragma unroll
    for (int ee = 0; ee < EB; ++ee) acc[ee] = 0.f;
    for (int k = 0; k < 136; ++k) {
        float w = W2a[k * 256 + t];
#pragma unroll
        for (int ee = 0; ee < EB; ++ee) acc[ee] = fmaf(M[ee][k], w, acc[ee]);
    }
#pragma unroll
    for (int ee = 0; ee < EB; ++ee) P[ee][t] = silu(acc[ee]);
    __syncthreads();
#pragma unroll
    for (int ee = 0; ee < EB; ++ee) acc[ee] = 0.f;
    for (int k = 0; k < 256; ++k) {
        float w = W2b[k * 256 + t];
#pragma unroll
        for (int ee = 0; ee < EB; ++ee) acc[ee] = fmaf(P[ee][k], w, acc[ee]);
    }
#pragma unroll
    for (int ee = 0; ee < EB; ++ee) Q[ee][t] = s_cut[ee] * silu(acc[ee]);
    __syncthreads();
}

// ---------------------------------------------------------------- K1: latents0 + (lat0@Wenv0[:,96:192]) + scatter -> env
__global__ __launch_bounds__(256) void k1_lat_scatter0(
    const float* __restrict__ nodeinv, const float* __restrict__ edgeinv,
    const float* __restrict__ elen, const float* __restrict__ edge_attr,
    const int* __restrict__ eidx, const float* __restrict__ W2a,
    const float* __restrict__ W2b, const float* __restrict__ Wenv0,
    float* __restrict__ env) {
    __shared__ float P[EB][256], Q[EB][256], M[EB][140];
    __shared__ float s_cut[EB];
    int t = threadIdx.x;
    int e0 = blockIdx.x * EB;
    compute_lat0(nodeinv, edgeinv, elen, eidx, W2a, W2b, e0, t, P, Q, M, s_cut);
    if (t < 192) {
        int col = t % 96, half = t / 96;
        float a[8];
#pragma unroll
        for (int i = 0; i < 8; ++i) a[i] = 0.f;
        for (int k = 0; k < 256; ++k) {
            float w = Wenv0[k * 192 + 96 + col];
#pragma unroll
            for (int i = 0; i < 8; ++i) a[i] = fmaf(Q[half * 8 + i][k], w, a[i]);
        }
#pragma unroll
        for (int i = 0; i < 8; ++i) M[half * 8 + i][col] = a[i];
    }
    __syncthreads();
    for (int i = t; i < EB * 32; i += 256) {
        int el = i >> 5, k = i & 31;
        int e = e0 + el;
        float cw = s_cut[el];
        int n = eidx[e];
        float w0 = M[el][k * 3 + 0] * cw;
        float w1 = M[el][k * 3 + 1] * cw;
        float w2 = M[el][k * 3 + 2] * cw;
        float* dst = env + (size_t)n * 288 + k;
#pragma unroll
        for (int m = 0; m < 9; ++m) {
            float w = (m == 0) ? w0 : ((m < 4) ? w1 : w2);
            atomicAdd(dst + m * 32, edge_attr[(size_t)e * 9 + m] * w);
        }
    }
}

// ---------------------------------------------------------------- node transform (mix -> prod -> mix), env layout (N, 9, 32)
__global__ __launch_bounds__(288) void k_node(
    const float* envin, const float* __restrict__ nodeinv,
    const float* __restrict__ Wenvlin, const float* __restrict__ Wprod,
    const float* __restrict__ Wfeat, float* featOut) {
    __shared__ float s_env[288];
    __shared__ float s_inv[64];
    __shared__ float s_mix[288];
    __shared__ float s_ew[96];
    int n = blockIdx.x;
    int t = threadIdx.x;
    s_env[t] = envin[(size_t)n * 288 + t] * (1.0f / 32.0f);
    if (t < 64) s_inv[t] = nodeinv[n * 64 + t];
    __syncthreads();
    int m = t >> 5, j = t & 31;
    int l = (m == 0) ? 0 : ((m < 4) ? 1 : 2);
    float a = 0.f;
    for (int k = 0; k < 32; ++k) a = fmaf(s_env[m * 32 + k], Wenvlin[l * 1024 + k * 32 + j], a);
    if (t < 96) {
        int c = t >> 5, jj = t & 31;
        float b = 0.f;
        for (int tt = 0; tt < 64; ++tt) b = fmaf(s_inv[tt], Wprod[c * 2048 + tt * 32 + jj], b);
        s_ew[t] = b;
    }
    s_mix[t] = a;
    __syncthreads();
    float s = s_mix[j];
    float p = s_mix[t] * (s_ew[j] + s_ew[32 + j] * s + s_ew[64 + j] * s * s);
    __syncthreads();
    s_env[t] = p;
    __syncthreads();
    float o = 0.f;
    for (int jl = 0; jl < 32; ++jl) o = fmaf(s_env[m * 32 + jl], Wfeat[l * 1024 + jl * 32 + j], o);
    featOut[(size_t)n * 288 + t] = o;
}

// ---------------------------------------------------------------- K3: latents0 -> latents1 -> (lat1@Wenv1) + scatter -> env
__global__ __launch_bounds__(256) void k3_update_scatter1(
    const float* __restrict__ nodeinv, const float* __restrict__ edgeinv,
    const float* __restrict__ elen, const float* __restrict__ edge_attr,
    const int* __restrict__ eidx, const float* __restrict__ W2a,
    const float* __restrict__ W2b, const float* __restrict__ Wl1a,
    const float* __restrict__ Wl1b, const float* __restrict__ Wenv1,
    const float* __restrict__ featN0, float* __restrict__ env) {
    __shared__ float P[EB][256], Q[EB][256], M[EB][140];
    __shared__ float s_cut[EB];
    int t = threadIdx.x;
    int e0 = blockIdx.x * EB;
    compute_lat0(nodeinv, edgeinv, elen, eidx, W2a, W2b, e0, t, P, Q, M, s_cut);
    // l_norms of featN0[center] into M[.][0..95]
    for (int i = t; i < EB * 96; i += 256) {
        int ee = i / 96, rem = i - ee * 96;
        int l = rem >> 5, kk = rem & 31;
        int off = (l == 0) ? 0 : ((l == 1) ? 1 : 4);
        int d = (l == 0) ? 1 : ((l == 1) ? 3 : 5);
        const float* f = featN0 + (size_t)eidx[e0 + ee] * 288 + kk;
        float s = 1e-8f;
        for (int mm = off; mm < off + d; ++mm) { float x = f[mm * 32]; s = fmaf(x, x, s); }
        M[ee][rem] = sqrtf(s);
    }
    __syncthreads();
    float acc[EB];
#pragma unroll
    for (int ee = 0; ee < EB; ++ee) acc[ee] = 0.f;
    for (int k = 0; k < 256; ++k) {
        float w = Wl1a[k * 256 + t];
#pragma unroll
        for (int ee = 0; ee < EB; ++ee) acc[ee] = fmaf(Q[ee][k], w, acc[ee]);
    }
    for (int k = 0; k < 96; ++k) {
        float w = Wl1a[(256 + k) * 256 + t];
#pragma unroll
        for (int ee = 0; ee < EB; ++ee) acc[ee] = fmaf(M[ee][k], w, acc[ee]);
    }
#pragma unroll
    for (int ee = 0; ee < EB; ++ee) P[ee][t] = silu(acc[ee]);
    __syncthreads();
#pragma unroll
    for (int ee = 0; ee < EB; ++ee) acc[ee] = 0.f;
    for (int k = 0; k < 256; ++k) {
        float w = Wl1b[k * 256 + t];
#pragma unroll
        for (int ee = 0; ee < EB; ++ee) acc[ee] = fmaf(P[ee][k], w, acc[ee]);
    }
#pragma unroll
    for (int ee = 0; ee < EB; ++ee)
        Q[ee][t] = 0.8944271909999159f * Q[ee][t] +
                   0.4472135954999579f * s_cut[ee] * silu(acc[ee]);
    __syncthreads();
    if (t < 192) {
        int col = t % 96, half = t / 96;
        float a[8];
#pragma unroll
        for (int i = 0; i < 8; ++i) a[i] = 0.f;
        for (int k = 0; k < 256; ++k) {
            float w = Wenv1[k * 96 + col];
#pragma unroll
            for (int i = 0; i < 8; ++i) a[i] = fmaf(Q[half * 8 + i][k], w, a[i]);
        }
#pragma unroll
        for (int i = 0; i < 8; ++i) M[half * 8 + i][col] = a[i];
    }
    __syncthreads();
    for (int i = t; i < EB * 32; i += 256) {
        int el = i >> 5, k = i & 31;
        int e = e0 + el;
        float cw = s_cut[el];
        int n = eidx[e];
        float w0 = M[el][k * 3 + 0] * cw;
        float w1 = M[el][k * 3 + 1] * cw;
        float w2 = M[el][k * 3 + 2] * cw;
        float* dst = env + (size_t)n * 288 + k;
#pragma unroll
        for (int m = 0; m < 9; ++m) {
            float w = (m == 0) ? w0 : ((m < 4) ? w1 : w2);
            atomicAdd(dst + m * 32, edge_attr[(size_t)e * 9 + m] * w);
        }
    }
}

// ---------------------------------------------------------------- K5: recompute lat0->w0, lat1; S; MFMA Wfinlat contraction; readout
__global__ __launch_bounds__(256) void k5_final(
    const float* __restrict__ nodeinv, const float* __restrict__ edgeinv,
    const float* __restrict__ elen, const float* __restrict__ edge_attr,
    const int* __restrict__ eidx, const float* __restrict__ W2a,
    const float* __restrict__ W2b, const float* __restrict__ Wenv0,
    const float* __restrict__ Wl1a, const float* __restrict__ Wl1b,
    const _Float16* __restrict__ WfinT, const float* __restrict__ Wro1,
    const float* __restrict__ Wro2, const float* __restrict__ featN0,
    const float* __restrict__ featN1, float* __restrict__ out) {
    __shared__ float P[EB][256], Q[EB][256], M[EB][140];
    __shared__ float s_w0[EB][96], s_S[EB][96], s_scal[EB][96];
    __shared__ float s_out[EB][9];
    __shared__ float s_cut[EB];
    int t = threadIdx.x;
    int e0 = blockIdx.x * EB;
    compute_lat0(nodeinv, edgeinv, elen, eidx, W2a, W2b, e0, t, P, Q, M, s_cut);
    // w0 = lat0 @ Wenv0[:, 0:96] -> s_w0 ; l_norms -> M (independent)
    if (t < 192) {
        int col = t % 96, half = t / 96;
        float a[8];
#pragma unroll
        for (int i = 0; i < 8; ++i) a[i] = 0.f;
        for (int k = 0; k < 256; ++k) {
            float w = Wenv0[k * 192 + col];
#pragma unroll
            for (int i = 0; i < 8; ++i) a[i] = fmaf(Q[half * 8 + i][k], w, a[i]);
        }
#pragma unroll
        for (int i = 0; i < 8; ++i) s_w0[half * 8 + i][col] = a[i];
    }
    for (int i = t; i < EB * 96; i += 256) {
        int ee = i / 96, rem = i - ee * 96;
        int l = rem >> 5, kk = rem & 31;
        int off = (l == 0) ? 0 : ((l == 1) ? 1 : 4);
        int d = (l == 0) ? 1 : ((l == 1) ? 3 : 5);
        const float* f = featN0 + (size_t)eidx[e0 + ee] * 288 + kk;
        float s = 1e-8f;
        for (int mm = off; mm < off + d; ++mm) { float x = f[mm * 32]; s = fmaf(x, x, s); }
        M[ee][rem] = sqrtf(s);
    }
    __syncthreads();
    float acc[EB];
#pragma unroll
    for (int ee = 0; ee < EB; ++ee) acc[ee] = 0.f;
    for (int k = 0; k < 256; ++k) {
        float w = Wl1a[k * 256 + t];
#pragma unroll
        for (int ee = 0; ee < EB; ++ee) acc[ee] = fmaf(Q[ee][k], w, acc[ee]);
    }
    for (int k = 0; k < 96; ++k) {
        float w = Wl1a[(256 + k) * 256 + t];
#pragma unroll
        for (int ee = 0; ee < EB; ++ee) acc[ee] = fmaf(M[ee][k], w, acc[ee]);
    }
#pragma unroll
    for (int ee = 0; ee < EB; ++ee) P[ee][t] = silu(acc[ee]);
    __syncthreads();
#pragma unroll
    for (int ee = 0; ee < EB; ++ee) acc[ee] = 0.f;
    for (int k = 0; k < 256; ++k) {
        float w = Wl1b[k * 256 + t];
#pragma unroll
        for (int ee = 0; ee < EB; ++ee) acc[ee] = fmaf(P[ee][k], w, acc[ee]);
    }
#pragma unroll
    for (int ee = 0; ee < EB; ++ee)
        Q[ee][t] = 0.8944271909999159f * Q[ee][t] +
                   0.4472135954999579f * s_cut[ee] * silu(acc[ee]);
    __syncthreads();  // Q (lat1) final; P now dead -> overlay Qh
    // Qh (f16 copy of Q, row stride 264) into P's storage; S from featN1
    _Float16* Qh = (_Float16*)&P[0][0];
    for (int i = t; i < EB * 256; i += 256) {
        int m = i >> 8, c = i & 255;
        Qh[m * 264 + c] = (_Float16)Q[m][c];
    }
    for (int i = t; i < EB * 96; i += 256) {
        int ee = i / 96, rem = i - ee * 96;
        int l = rem >> 5, kk = rem & 31;
        int off = (l == 0) ? 0 : ((l == 1) ? 1 : 4);
        int d = (l == 0) ? 1 : ((l == 1) ? 3 : 5);
        int e = e0 + ee;
        const float* f = featN1 + (size_t)eidx[e] * 288 + kk;
        float s = 0.f;
        for (int mm = off; mm < off + d; ++mm)
            s = fmaf(f[mm * 32], edge_attr[(size_t)e * 9 + mm], s);
        s_S[ee][rem] = s;
    }
    __syncthreads();
    // ---- MFMA phase: wfin[m, n] = sum_c Q[m,c] WfinT[n, c]; scal-partials over k_env
    {
        int wave = t >> 6, lane = t & 63;
        int n15 = lane & 15, mb = (lane >> 4) * 4;
        f16x8 afrag[8];
        {
            const _Float16* qrow = Qh + n15 * 264 + (lane >> 4) * 8;
#pragma unroll
            for (int cc = 0; cc < 8; ++cc)
                afrag[cc] = *(const f16x8*)(qrow + cc * 32);
        }
        int ncombo = (wave < 2) ? 2 : 1;
        for (int ci = 0; ci < ncombo; ++ci) {
            int combo = wave + ci * 4;
            int l = combo >> 1, j0 = (combo & 1) * 16;
            f32x4 run = {0.f, 0.f, 0.f, 0.f};
            for (int ke = 0; ke < 32; ++ke) {
                int n0 = l * 1024 + ke * 32 + j0;
                const _Float16* bbase =
                    WfinT + (size_t)(n0 + n15) * 256 + (lane >> 4) * 8;
                f32x4 ac = {0.f, 0.f, 0.f, 0.f};
#pragma unroll
                for (int cc = 0; cc < 8; ++cc) {
                    f16x8 b = *(const f16x8*)(bbase + cc * 32);
                    ac = __builtin_amdgcn_mfma_f32_16x16x32_f16(afrag[cc], b, ac, 0, 0, 0);
                }
#pragma unroll
                for (int i2 = 0; i2 < 4; ++i2)
                    run[i2] = fmaf(ac[i2], s_S[mb + i2][l * 32 + ke], run[i2]);
            }
#pragma unroll
            for (int i2 = 0; i2 < 4; ++i2)
                s_scal[mb + i2][l * 32 + j0 + n15] =
                    s_w0[mb + i2][(j0 + n15) * 3 + l] * run[i2];
        }
    }
    __syncthreads();
    // readout
    float r[EB];
#pragma unroll
    for (int ee = 0; ee < EB; ++ee) r[ee] = 0.f;
    for (int kk = 0; kk < 256; ++kk) {
        float w = Wro1[kk * 256 + t];
#pragma unroll
        for (int ee = 0; ee < EB; ++ee) r[ee] = fmaf(Q[ee][kk], w, r[ee]);
    }
    for (int kk = 0; kk < 96; ++kk) {
        float w = Wro1[(256 + kk) * 256 + t];
#pragma unroll
        for (int ee = 0; ee < EB; ++ee) r[ee] = fmaf(s_scal[ee][kk], w, r[ee]);
    }
    float w2 = Wro2[t];
#pragma unroll
    for (int ee = 0; ee < EB; ++ee) M[ee][t % 140] = 0.f;  // (dummy to keep M live region clear)
#pragma unroll
    for (int ee = 0; ee < EB; ++ee) Q[ee][t] = silu(r[ee]) * w2;
    __syncthreads();
    if (t < 128) {
        int ee = t >> 3, part = t & 7;
        float s = 0.f;
        for (int c2 = 0; c2 < 32; ++c2) s += Q[ee][part * 32 + ((c2 + ee) & 31)];
        s_out[ee][part] = s;
    }
    __syncthreads();
    if (t < EB) {
        float tot = 0.f;
#pragma unroll
        for (int p = 0; p < 8; ++p) tot += s_out[t][p];
        out[e0 + t] = tot;
    }
}

// ----------------------------------------------------------------
extern "C" void kernel_launch(void* const* d_in, const int* in_sizes, int n_in,
                              void* d_out, int out_size, void* d_ws, size_t ws_size,
                              hipStream_t stream) {
    (void)in_sizes; (void)n_in; (void)out_size;
    const float* edge_attr = (const float*)d_in[0];
    const float* edge_len  = (const float*)d_in[1];
    const float* edge_inv  = (const float*)d_in[2];
    const float* node_inv  = (const float*)d_in[3];
    const float* W2a     = (const float*)d_in[4];
    const float* W2b     = (const float*)d_in[5];
    const float* Wl1a    = (const float*)d_in[6];
    const float* Wl1b    = (const float*)d_in[7];
    const float* Wenv0   = (const float*)d_in[8];
    const float* Wenv1   = (const float*)d_in[9];
    const float* Wenvlin = (const float*)d_in[10];
    const float* Wprod   = (const float*)d_in[11];
    const float* Wfeat   = (const float*)d_in[12];
    const float* Wfinlat = (const float*)d_in[13];
    const float* Wro1    = (const float*)d_in[14];
    const float* Wro2    = (const float*)d_in[15];
    const int* eidx      = (const int*)d_in[16];
    float* out = (float*)d_out;

    // ws: WfinT (3072*256 f16 = 1.5MB) + env + featN0 (2 * 10000*288 f32 = 23.04MB)
    size_t need = (size_t)3072 * 256 * sizeof(_Float16) +
                  (size_t)2 * NNODES * 288 * sizeof(float);
    if (ws_size < need) return;  // absmax==0.318 next round => ws in [23.0,24.6) MB
    _Float16* WfinT = (_Float16*)d_ws;
    float* env    = (float*)((char*)d_ws + (size_t)3072 * 256 * sizeof(_Float16));
    float* featN0 = env + (size_t)NNODES * 288;

    const int ENV_N = NNODES * 288;
    k_wfin<<<3072, 256, 0, stream>>>(Wfinlat, WfinT);
    k_zero<<<(ENV_N + 255) / 256, 256, 0, stream>>>(env, ENV_N);
    k1_lat_scatter0<<<NBLK, 256, 0, stream>>>(node_inv, edge_inv, edge_len, edge_attr,
                                              eidx, W2a, W2b, Wenv0, env);
    k_node<<<NNODES, 288, 0, stream>>>(env, node_inv, Wenvlin, Wprod, Wfeat, featN0);
    k_zero<<<(ENV_N + 255) / 256, 256, 0, stream>>>(env, ENV_N);
    k3_update_scatter1<<<NBLK, 256, 0, stream>>>(node_inv, edge_inv, edge_len, edge_attr,
                                                 eidx, W2a, W2b, Wl1a, Wl1b, Wenv1,
                                                 featN0, env);
    k_node<<<NNODES, 288, 0, stream>>>(env, node_inv, Wenvlin + 3072, Wprod + 6144,
                                       Wfeat + 3072, env);  // in-place: env1 -> featN1
    k5_final<<<NBLK, 256, 0, stream>>>(node_inv, edge_inv, edge_len, edge_attr, eidx,
                                       W2a, W2b, Wenv0, Wl1a, Wl1b, WfinT, Wro1, Wro2,
                                       featN0, env, out);
}

// Round 5
// 10529.855 us; speedup vs baseline: 2.3712x; 1.7076x over previous
//
#include <hip/hip_runtime.h>
#include <math.h>

#define NE 320000
#define NNODES 10000
#define EB 16
#define NBLK (NE / EB)
#define AST 360   // Ah stride (f16 elems)
#define BST 264   // AhB stride (f16 elems)

typedef _Float16 f16x8 __attribute__((ext_vector_type(8)));
typedef float f32x4 __attribute__((ext_vector_type(4)));

__device__ __forceinline__ float silu(float x) { return x / (1.0f + __expf(-x)); }
__device__ __forceinline__ float cutf(float len) {
    float x = len * (1.0f / 6.0f);
    float x2 = x * x, x6 = x2 * x2 * x2;
    float f = 1.0f - 28.0f * x6 + 48.0f * x6 * x - 21.0f * x6 * x2;
    return (x < 1.0f) ? f : 0.0f;
}

// ---------------------------------------------------------------- zero
__global__ __launch_bounds__(256) void k_zero(float* __restrict__ p, int n) {
    int i = blockIdx.x * 256 + threadIdx.x;
    if (i < n) p[i] = 0.f;
}

// ---------------------------------------------------------------- pack: src[K x N] (row k, stride) -> dst[N][Kpad] f16
__global__ __launch_bounds__(256) void k_pack(const float* __restrict__ src,
                                              _Float16* __restrict__ dst,
                                              int K, int Kpad, int N, int stride,
                                              int colOff) {
    int i = blockIdx.x * 256 + threadIdx.x;
    if (i >= N * Kpad) return;
    int n = i / Kpad, k = i - n * Kpad;
    dst[(size_t)n * Kpad + k] = (k < K) ? (_Float16)src[(size_t)k * stride + colOff + n]
                                        : (_Float16)0.f;
}

// ---------------------------------------------------------------- MFMA GEMM: Y[16 x NT*16] = A[16 x ksteps*32] @ Wt^T
// A in LDS f16 (stride astride); Wt global f16 [NT*16][K].
template <int NT>
__device__ __forceinline__ void mfma_gemm(int ksteps, const _Float16* Ah, int astride,
                                          const _Float16* __restrict__ Wt, int K,
                                          int t, f32x4* acc) {
    int wave = t >> 6, r = t & 15, g = (t & 63) >> 4;
    const int TPW = (NT + 3) / 4;
#pragma unroll
    for (int i = 0; i < TPW; ++i) acc[i] = (f32x4){0.f, 0.f, 0.f, 0.f};
    for (int ks = 0; ks < ksteps; ++ks) {
        f16x8 a = *(const f16x8*)(Ah + r * astride + ks * 32 + g * 8);
#pragma unroll
        for (int i = 0; i < TPW; ++i) {
            int nt = wave + 4 * i;
            if (nt < NT) {
                f16x8 b = *(const f16x8*)(Wt + (size_t)(nt * 16 + r) * K + ks * 32 + g * 8);
                acc[i] = __builtin_amdgcn_mfma_f32_16x16x32_f16(a, b, acc[i], 0, 0, 0);
            }
        }
    }
}

// gather lat_in -> Ah cols 0..159 (f16), compute s_cut
__device__ __forceinline__ void gather_latin(
    const float* __restrict__ nodeinv, const float* __restrict__ edgeinv,
    const float* __restrict__ elen, const int* __restrict__ eidx,
    int e0, int t, _Float16* Ah, float* s_cut) {
    if (t < EB) s_cut[t] = cutf(elen[e0 + t]);
    for (int i = t; i < EB * 160; i += 256) {
        int ee = i / 160, k = i - ee * 160;
        int e = e0 + ee;
        float v;
        if (k < 64)       v = nodeinv[eidx[e] * 64 + k];
        else if (k < 128) v = nodeinv[eidx[NE + e] * 64 + (k - 64)];
        else if (k < 136) v = edgeinv[(size_t)e * 8 + (k - 128)];
        else              v = 0.f;
        Ah[ee * AST + k] = (_Float16)v;
    }
}

// GEMM1+GEMM2: lat0 -> Q(f32, optional) and Ah cols 0..255 (f16)
__device__ __forceinline__ void lat0_mfma(const _Float16* W2aT, const _Float16* W2bT,
                                          int t, _Float16* Ah, _Float16* AhB,
                                          float (*Q)[256], const float* s_cut) {
    int wave = t >> 6, r = t & 15, g = (t & 63) >> 4;
    f32x4 acc[4];
    mfma_gemm<16>(5, Ah, AST, W2aT, 160, t, acc);
#pragma unroll
    for (int i = 0; i < 4; ++i) {
        int nt = wave + 4 * i;
#pragma unroll
        for (int i2 = 0; i2 < 4; ++i2)
            AhB[(g * 4 + i2) * BST + nt * 16 + r] = (_Float16)silu(acc[i][i2]);
    }
    __syncthreads();
    mfma_gemm<16>(8, AhB, BST, W2bT, 256, t, acc);
#pragma unroll
    for (int i = 0; i < 4; ++i) {
        int nt = wave + 4 * i;
#pragma unroll
        for (int i2 = 0; i2 < 4; ++i2) {
            int ro = g * 4 + i2, col = nt * 16 + r;
            float v = s_cut[ro] * silu(acc[i][i2]);
            if (Q) Q[ro][col] = v;
            Ah[ro * AST + col] = (_Float16)v;
        }
    }
    __syncthreads();
}

// lnorm(featN[center]) -> Ah cols 256..351 f16
__device__ __forceinline__ void gather_lnorm(const float* __restrict__ featN,
                                             const int* __restrict__ eidx,
                                             int e0, int t, _Float16* Ah) {
    for (int i = t; i < EB * 96; i += 256) {
        int ee = i / 96, rem = i - ee * 96;
        int l = rem >> 5, kk = rem & 31;
        int off = (l == 0) ? 0 : ((l == 1) ? 1 : 4);
        int d = (l == 0) ? 1 : ((l == 1) ? 3 : 5);
        const float* f = featN + (size_t)eidx[e0 + ee] * 288 + kk;
        float s = 1e-8f;
        for (int mm = off; mm < off + d; ++mm) { float x = f[mm * 32]; s = fmaf(x, x, s); }
        Ah[ee * AST + 256 + rem] = (_Float16)sqrtf(s);
    }
}

// scatter env += weight_channels(sh, s_w)*cut
__device__ __forceinline__ void scatter_env(const float* __restrict__ edge_attr,
                                            const int* __restrict__ eidx,
                                            const float (*s_w)[96], const float* s_cut,
                                            int e0, int t, float* __restrict__ env) {
    for (int i = t; i < EB * 32; i += 256) {
        int el = i >> 5, k = i & 31;
        int e = e0 + el;
        float cw = s_cut[el];
        int n = eidx[e];
        float w0 = s_w[el][k * 3 + 0] * cw;
        float w1 = s_w[el][k * 3 + 1] * cw;
        float w2 = s_w[el][k * 3 + 2] * cw;
        float* dst = env + (size_t)n * 288 + k;
#pragma unroll
        for (int m = 0; m < 9; ++m) {
            float w = (m == 0) ? w0 : ((m < 4) ? w1 : w2);
            atomicAdd(dst + m * 32, edge_attr[(size_t)e * 9 + m] * w);
        }
    }
}

// ---------------------------------------------------------------- K1: lat0 + (lat0@Wenv0b) + scatter
__global__ __launch_bounds__(256) void k1_lat_scatter0(
    const float* __restrict__ nodeinv, const float* __restrict__ edgeinv,
    const float* __restrict__ elen, const float* __restrict__ edge_attr,
    const int* __restrict__ eidx, const _Float16* __restrict__ W2aT,
    const _Float16* __restrict__ W2bT, const _Float16* __restrict__ Wenv0bT,
    float* __restrict__ env) {
    __shared__ alignas(16) _Float16 Ah[EB * AST];
    __shared__ alignas(16) _Float16 AhB[EB * BST];
    __shared__ float s_w[EB][96];
    __shared__ float s_cut[EB];
    int t = threadIdx.x;
    int e0 = blockIdx.x * EB;
    int wave = t >> 6, r = t & 15, g = (t & 63) >> 4;
    gather_latin(nodeinv, edgeinv, elen, eidx, e0, t, Ah, s_cut);
    __syncthreads();
    lat0_mfma(W2aT, W2bT, t, Ah, AhB, nullptr, s_cut);
    f32x4 acc[4];
    mfma_gemm<6>(8, Ah, AST, Wenv0bT, 256, t, acc);
#pragma unroll
    for (int i = 0; i < 2; ++i) {
        int nt = wave + 4 * i;
        if (nt < 6) {
#pragma unroll
            for (int i2 = 0; i2 < 4; ++i2)
                s_w[g * 4 + i2][nt * 16 + r] = acc[i][i2];
        }
    }
    __syncthreads();
    scatter_env(edge_attr, eidx, s_w, s_cut, e0, t, env);
}

// ---------------------------------------------------------------- node transform (unchanged)
__global__ __launch_bounds__(288) void k_node(
    const float* envin, const float* __restrict__ nodeinv,
    const float* __restrict__ Wenvlin, const float* __restrict__ Wprod,
    const float* __restrict__ Wfeat, float* featOut) {
    __shared__ float s_env[288];
    __shared__ float s_inv[64];
    __shared__ float s_mix[288];
    __shared__ float s_ew[96];
    int n = blockIdx.x;
    int t = threadIdx.x;
    s_env[t] = envin[(size_t)n * 288 + t] * (1.0f / 32.0f);
    if (t < 64) s_inv[t] = nodeinv[n * 64 + t];
    __syncthreads();
    int m = t >> 5, j = t & 31;
    int l = (m == 0) ? 0 : ((m < 4) ? 1 : 2);
    float a = 0.f;
    for (int k = 0; k < 32; ++k) a = fmaf(s_env[m * 32 + k], Wenvlin[l * 1024 + k * 32 + j], a);
    if (t < 96) {
        int c = t >> 5, jj = t & 31;
        float b = 0.f;
        for (int tt = 0; tt < 64; ++tt) b = fmaf(s_inv[tt], Wprod[c * 2048 + tt * 32 + jj], b);
        s_ew[t] = b;
    }
    s_mix[t] = a;
    __syncthreads();
    float s = s_mix[j];
    float p = s_mix[t] * (s_ew[j] + s_ew[32 + j] * s + s_ew[64 + j] * s * s);
    __syncthreads();
    s_env[t] = p;
    __syncthreads();
    float o = 0.f;
    for (int jl = 0; jl < 32; ++jl) o = fmaf(s_env[m * 32 + jl], Wfeat[l * 1024 + jl * 32 + j], o);
    featOut[(size_t)n * 288 + t] = o;
}

// ---------------------------------------------------------------- K3: lat0 -> lat1 -> (lat1@Wenv1) + scatter
__global__ __launch_bounds__(256) void k3_update_scatter1(
    const float* __restrict__ nodeinv, const float* __restrict__ edgeinv,
    const float* __restrict__ elen, const float* __restrict__ edge_attr,
    const int* __restrict__ eidx, const _Float16* __restrict__ W2aT,
    const _Float16* __restrict__ W2bT, const _Float16* __restrict__ Wl1aT,
    const _Float16* __restrict__ Wl1bT, const _Float16* __restrict__ Wenv1T,
    const float* __restrict__ featN0, float* __restrict__ env) {
    __shared__ alignas(16) _Float16 Ah[EB * AST];
    __shared__ alignas(16) _Float16 AhB[EB * BST];
    __shared__ float Q[EB][256];
    __shared__ float s_w[EB][96];
    __shared__ float s_cut[EB];
    int t = threadIdx.x;
    int e0 = blockIdx.x * EB;
    int wave = t >> 6, r = t & 15, g = (t & 63) >> 4;
    gather_latin(nodeinv, edgeinv, elen, eidx, e0, t, Ah, s_cut);
    gather_lnorm(featN0, eidx, e0, t, Ah);
    __syncthreads();
    lat0_mfma(W2aT, W2bT, t, Ah, AhB, Q, s_cut);
    f32x4 acc[4];
    // lat1
    mfma_gemm<16>(11, Ah, AST, Wl1aT, 352, t, acc);
#pragma unroll
    for (int i = 0; i < 4; ++i) {
        int nt = wave + 4 * i;
#pragma unroll
        for (int i2 = 0; i2 < 4; ++i2)
            AhB[(g * 4 + i2) * BST + nt * 16 + r] = (_Float16)silu(acc[i][i2]);
    }
    __syncthreads();
    mfma_gemm<16>(8, AhB, BST, Wl1bT, 256, t, acc);
#pragma unroll
    for (int i = 0; i < 4; ++i) {
        int nt = wave + 4 * i;
#pragma unroll
        for (int i2 = 0; i2 < 4; ++i2) {
            int ro = g * 4 + i2, col = nt * 16 + r;
            float v = 0.8944271909999159f * Q[ro][col] +
                      0.4472135954999579f * s_cut[ro] * silu(acc[i][i2]);
            Ah[ro * AST + col] = (_Float16)v;
        }
    }
    __syncthreads();
    mfma_gemm<6>(8, Ah, AST, Wenv1T, 256, t, acc);
#pragma unroll
    for (int i = 0; i < 2; ++i) {
        int nt = wave + 4 * i;
        if (nt < 6) {
#pragma unroll
            for (int i2 = 0; i2 < 4; ++i2)
                s_w[g * 4 + i2][nt * 16 + r] = acc[i][i2];
        }
    }
    __syncthreads();
    scatter_env(edge_attr, eidx, s_w, s_cut, e0, t, env);
}

// ---------------------------------------------------------------- K5: lat0 -> w0, lat1; S; Wfinlat MFMA; readout
__global__ __launch_bounds__(256) void k5_final(
    const float* __restrict__ nodeinv, const float* __restrict__ edgeinv,
    const float* __restrict__ elen, const float* __restrict__ edge_attr,
    const int* __restrict__ eidx, const _Float16* __restrict__ W2aT,
    const _Float16* __restrict__ W2bT, const _Float16* __restrict__ Wenv0aT,
    const _Float16* __restrict__ Wl1aT, const _Float16* __restrict__ Wl1bT,
    const _Float16* __restrict__ WfinT, const _Float16* __restrict__ Wro1T,
    const float* __restrict__ Wro2, const float* __restrict__ featN0,
    const float* __restrict__ featN1, float* __restrict__ out) {
    __shared__ alignas(16) _Float16 Ah[EB * AST];
    __shared__ alignas(16) _Float16 AhB[EB * BST];
    __shared__ float Q[EB][256];
    __shared__ float s_w0[EB][96], s_S[EB][96], s_scal[EB][96];
    __shared__ float s_out[EB][9];
    __shared__ float s_cut[EB];
    int t = threadIdx.x;
    int e0 = blockIdx.x * EB;
    int wave = t >> 6, r = t & 15, g = (t & 63) >> 4;
    gather_latin(nodeinv, edgeinv, elen, eidx, e0, t, Ah, s_cut);
    gather_lnorm(featN0, eidx, e0, t, Ah);
    // S[e,l,k] = sum_m featN1[center,m,k]*sh[e,m]
    for (int i = t; i < EB * 96; i += 256) {
        int ee = i / 96, rem = i - ee * 96;
        int l = rem >> 5, kk = rem & 31;
        int off = (l == 0) ? 0 : ((l == 1) ? 1 : 4);
        int d = (l == 0) ? 1 : ((l == 1) ? 3 : 5);
        int e = e0 + ee;
        const float* f = featN1 + (size_t)eidx[e] * 288 + kk;
        float s = 0.f;
        for (int mm = off; mm < off + d; ++mm)
            s = fmaf(f[mm * 32], edge_attr[(size_t)e * 9 + mm], s);
        s_S[ee][rem] = s;
    }
    __syncthreads();
    lat0_mfma(W2aT, W2bT, t, Ah, AhB, Q, s_cut);
    f32x4 acc[4];
    // w0 = lat0 @ Wenv0[:,0:96]
    mfma_gemm<6>(8, Ah, AST, Wenv0aT, 256, t, acc);
#pragma unroll
    for (int i = 0; i < 2; ++i) {
        int nt = wave + 4 * i;
        if (nt < 6) {
#pragma unroll
            for (int i2 = 0; i2 < 4; ++i2)
                s_w0[g * 4 + i2][nt * 16 + r] = acc[i][i2];
        }
    }
    // lat1
    mfma_gemm<16>(11, Ah, AST, Wl1aT, 352, t, acc);
#pragma unroll
    for (int i = 0; i < 4; ++i) {
        int nt = wave + 4 * i;
#pragma unroll
        for (int i2 = 0; i2 < 4; ++i2)
            AhB[(g * 4 + i2) * BST + nt * 16 + r] = (_Float16)silu(acc[i][i2]);
    }
    __syncthreads();
    mfma_gemm<16>(8, AhB, BST, Wl1bT, 256, t, acc);
#pragma unroll
    for (int i = 0; i < 4; ++i) {
        int nt = wave + 4 * i;
#pragma unroll
        for (int i2 = 0; i2 < 4; ++i2) {
            int ro = g * 4 + i2, col = nt * 16 + r;
            float v = 0.8944271909999159f * Q[ro][col] +
                      0.4472135954999579f * s_cut[ro] * silu(acc[i][i2]);
            Q[ro][col] = v;
            Ah[ro * AST + col] = (_Float16)v;
        }
    }
    __syncthreads();
    // ---- Wfinlat contraction (per R4, A from Ah stride AST)
    {
        int lane = t & 63;
        int n15 = lane & 15, g8 = lane >> 4, mb = g8 * 4;
        f16x8 afrag[8];
#pragma unroll
        for (int cc = 0; cc < 8; ++cc)
            afrag[cc] = *(const f16x8*)(Ah + n15 * AST + cc * 32 + g8 * 8);
        int ncombo = (wave < 2) ? 2 : 1;
        for (int ci = 0; ci < ncombo; ++ci) {
            int combo = wave + ci * 4;
            int l = combo >> 1, j0 = (combo & 1) * 16;
            f32x4 run = {0.f, 0.f, 0.f, 0.f};
            for (int ke = 0; ke < 32; ++ke) {
                int n0 = l * 1024 + ke * 32 + j0;
                const _Float16* bbase = WfinT + (size_t)(n0 + n15) * 256 + g8 * 8;
                f32x4 ac = {0.f, 0.f, 0.f, 0.f};
#pragma unroll
                for (int cc = 0; cc < 8; ++cc) {
                    f16x8 b = *(const f16x8*)(bbase + cc * 32);
                    ac = __builtin_amdgcn_mfma_f32_16x16x32_f16(afrag[cc], b, ac, 0, 0, 0);
                }
#pragma unroll
                for (int i2 = 0; i2 < 4; ++i2)
                    run[i2] = fmaf(ac[i2], s_S[mb + i2][l * 32 + ke], run[i2]);
            }
#pragma unroll
            for (int i2 = 0; i2 < 4; ++i2)
                s_scal[mb + i2][l * 32 + j0 + n15] =
                    s_w0[mb + i2][(j0 + n15) * 3 + l] * run[i2];
        }
    }
    __syncthreads();
    // scal -> Ah cols 256..351 (f16)
    for (int i = t; i < EB * 96; i += 256) {
        int ee = i / 96, c = i - ee * 96;
        Ah[ee * AST + 256 + c] = (_Float16)s_scal[ee][c];
    }
    __syncthreads();
    // readout GEMM
    mfma_gemm<16>(11, Ah, AST, Wro1T, 352, t, acc);
#pragma unroll
    for (int i = 0; i < 4; ++i) {
        int nt = wave + 4 * i;
#pragma unroll
        for (int i2 = 0; i2 < 4; ++i2) {
            int ro = g * 4 + i2, col = nt * 16 + r;
            Q[ro][col] = silu(acc[i][i2]) * Wro2[col];
        }
    }
    __syncthreads();
    if (t < 128) {
        int ee = t >> 3, part = t & 7;
        float s = 0.f;
        for (int c2 = 0; c2 < 32; ++c2) s += Q[ee][part * 32 + ((c2 + ee) & 31)];
        s_out[ee][part] = s;
    }
    __syncthreads();
    if (t < EB) {
        float tot = 0.f;
#pragma unroll
        for (int p = 0; p < 8; ++p) tot += s_out[t][p];
        out[e0 + t] = tot;
    }
}

// ----------------------------------------------------------------
extern "C" void kernel_launch(void* const* d_in, const int* in_sizes, int n_in,
                              void* d_out, int out_size, void* d_ws, size_t ws_size,
                              hipStream_t stream) {
    (void)in_sizes; (void)n_in; (void)out_size;
    const float* edge_attr = (const float*)d_in[0];
    const float* edge_len  = (const float*)d_in[1];
    const float* edge_inv  = (const float*)d_in[2];
    const float* node_inv  = (const float*)d_in[3];
    const float* W2a     = (const float*)d_in[4];
    const float* W2b     = (const float*)d_in[5];
    const float* Wl1a    = (const float*)d_in[6];
    const float* Wl1b    = (const float*)d_in[7];
    const float* Wenv0   = (const float*)d_in[8];
    const float* Wenv1   = (const float*)d_in[9];
    const float* Wenvlin = (const float*)d_in[10];
    const float* Wprod   = (const float*)d_in[11];
    const float* Wfeat   = (const float*)d_in[12];
    const float* Wfinlat = (const float*)d_in[13];
    const float* Wro1    = (const float*)d_in[14];
    const float* Wro2    = (const float*)d_in[15];
    const int* eidx      = (const int*)d_in[16];
    float* out = (float*)d_out;

    // ws: packed f16 weights (~2.31 MB) + env + featN0 (23.04 MB)
    _Float16* p = (_Float16*)d_ws;
    _Float16* WfinT   = p; p += 786432;   // [3072][256]
    _Float16* W2aT    = p; p += 40960;    // [256][160]
    _Float16* W2bT    = p; p += 65536;    // [256][256]
    _Float16* Wenv0aT = p; p += 24576;    // [96][256]
    _Float16* Wenv0bT = p; p += 24576;    // [96][256]
    _Float16* Wenv1T  = p; p += 24576;    // [96][256]
    _Float16* Wl1aT   = p; p += 90112;    // [256][352]
    _Float16* Wl1bT   = p; p += 65536;    // [256][256]
    _Float16* Wro1T   = p; p += 90112;    // [256][352]
    float* env    = (float*)p;
    float* featN0 = env + (size_t)NNODES * 288;
    size_t need = (size_t)((char*)(featN0 + (size_t)NNODES * 288) - (char*)d_ws);
    if (ws_size < need) return;  // absmax==0.318 signature => ws too small

    const int ENV_N = NNODES * 288;
    k_pack<<<3072, 256, 0, stream>>>(Wfinlat, WfinT, 256, 256, 3072, 3072, 0);
    k_pack<<<160, 256, 0, stream>>>(W2a, W2aT, 136, 160, 256, 256, 0);
    k_pack<<<256, 256, 0, stream>>>(W2b, W2bT, 256, 256, 256, 256, 0);
    k_pack<<<96, 256, 0, stream>>>(Wenv0, Wenv0aT, 256, 256, 96, 192, 0);
    k_pack<<<96, 256, 0, stream>>>(Wenv0, Wenv0bT, 256, 256, 96, 192, 96);
    k_pack<<<96, 256, 0, stream>>>(Wenv1, Wenv1T, 256, 256, 96, 96, 0);
    k_pack<<<352, 256, 0, stream>>>(Wl1a, Wl1aT, 352, 352, 256, 256, 0);
    k_pack<<<256, 256, 0, stream>>>(Wl1b, Wl1bT, 256, 256, 256, 256, 0);
    k_pack<<<352, 256, 0, stream>>>(Wro1, Wro1T, 352, 352, 256, 256, 0);

    k_zero<<<(ENV_N + 255) / 256, 256, 0, stream>>>(env, ENV_N);
    k1_lat_scatter0<<<NBLK, 256, 0, stream>>>(node_inv, edge_inv, edge_len, edge_attr,
                                              eidx, W2aT, W2bT, Wenv0bT, env);
    k_node<<<NNODES, 288, 0, stream>>>(env, node_inv, Wenvlin, Wprod, Wfeat, featN0);
    k_zero<<<(ENV_N + 255) / 256, 256, 0, stream>>>(env, ENV_N);
    k3_update_scatter1<<<NBLK, 256, 0, stream>>>(node_inv, edge_inv, edge_len, edge_attr,
                                                 eidx, W2aT, W2bT, Wl1aT, Wl1bT, Wenv1T,
                                                 featN0, env);
    k_node<<<NNODES, 288, 0, stream>>>(env, node_inv, Wenvlin + 3072, Wprod + 6144,
                                       Wfeat + 3072, env);  // in-place: env1 -> featN1
    k5_final<<<NBLK, 256, 0, stream>>>(node_inv, edge_inv, edge_len, edge_attr, eidx,
                                       W2aT, W2bT, Wenv0aT, Wl1aT, Wl1bT, WfinT, Wro1T,
                                       Wro2, featN0, env, out);
}

// Round 6
// 5603.296 us; speedup vs baseline: 4.4560x; 1.8792x over previous
//
#include <hip/hip_runtime.h>
#include <math.h>

#define NE 320000
#define NNODES 10000
#define EB 32
#define NBLK (NE / EB)
#define AST 360   // Ah stride (f16 elems)
#define BST 264   // AhB stride (f16 elems)

typedef _Float16 f16x8 __attribute__((ext_vector_type(8)));
typedef float f32x4 __attribute__((ext_vector_type(4)));

__device__ __forceinline__ float silu(float x) { return x / (1.0f + __expf(-x)); }
__device__ __forceinline__ float cutf(float len) {
    float x = len * (1.0f / 6.0f);
    float x2 = x * x, x6 = x2 * x2 * x2;
    float f = 1.0f - 28.0f * x6 + 48.0f * x6 * x - 21.0f * x6 * x2;
    return (x < 1.0f) ? f : 0.0f;
}

// ---------------------------------------------------------------- zero
__global__ __launch_bounds__(256) void k_zero(float* __restrict__ p, int n) {
    int i = blockIdx.x * 256 + threadIdx.x;
    if (i < n) p[i] = 0.f;
}

// ---------------------------------------------------------------- fragment-major pack for MLP weights
// src: W[K x N-ish] with row-stride `stride`, column colOff+n.
// dst[((nt*KS+ks)*64+lane)*8+j] = W[k=ks*32+(lane>>4)*8+j][colOff + nt*16 + (lane&15)]
__global__ __launch_bounds__(256) void k_packf(const float* __restrict__ src,
                                               _Float16* __restrict__ dst,
                                               int K, int KS, int NT, int stride,
                                               int colOff) {
    int i = blockIdx.x * 256 + threadIdx.x;
    if (i >= NT * KS * 512) return;
    int j = i & 7, lane = (i >> 3) & 63;
    int blk = i >> 9;
    int ks = blk % KS, nt = blk / KS;
    int k = ks * 32 + (lane >> 4) * 8 + j;
    int n = colOff + nt * 16 + (lane & 15);
    dst[i] = (k < K) ? (_Float16)src[(size_t)k * stride + n] : (_Float16)0.f;
}

// ---------------------------------------------------------------- fragment-major pack of Wfinlat (contraction B)
// dst[(((combo*32+ke)*8+cc)*64+lane)*8+j] = Wfin[c = cc*32+(lane>>4)*8+j][n]
//   n = (combo>>1)*1024 + ke*32 + (combo&1)*16 + (lane&15)
__global__ __launch_bounds__(256) void k_packfin(const float* __restrict__ W,
                                                 _Float16* __restrict__ dst) {
    int i = blockIdx.x * 256 + threadIdx.x;  // < 786432
    int j = i & 7, lane = (i >> 3) & 63, cc = (i >> 9) & 7, ke = (i >> 12) & 31,
        combo = i >> 17;
    int n = (combo >> 1) * 1024 + ke * 32 + (combo & 1) * 16 + (lane & 15);
    int c = cc * 32 + (lane >> 4) * 8 + j;
    dst[i] = (_Float16)W[(size_t)c * 3072 + n];
}

// ---------------------------------------------------------------- MFMA GEMM, 32 edges (2 m-tiles), frag-major B
template <int NT>
__device__ __forceinline__ void mfma_gemm2(int ksteps, const _Float16* Ah, int astride,
                                           const _Float16* __restrict__ Wt, int t,
                                           f32x4* acc0, f32x4* acc1) {
    int wave = t >> 6, lane = t & 63, r = lane & 15, g = lane >> 4;
    const int TPW = (NT + 3) / 4;
#pragma unroll
    for (int i = 0; i < TPW; ++i) {
        acc0[i] = (f32x4){0.f, 0.f, 0.f, 0.f};
        acc1[i] = (f32x4){0.f, 0.f, 0.f, 0.f};
    }
    for (int ks = 0; ks < ksteps; ++ks) {
        f16x8 a0 = *(const f16x8*)(Ah + r * astride + ks * 32 + g * 8);
        f16x8 a1 = *(const f16x8*)(Ah + (16 + r) * astride + ks * 32 + g * 8);
#pragma unroll
        for (int i = 0; i < TPW; ++i) {
            int nt = wave + 4 * i;
            if (nt < NT) {
                f16x8 b = *(const f16x8*)(Wt + ((size_t)(nt * ksteps + ks) * 64 + lane) * 8);
                acc0[i] = __builtin_amdgcn_mfma_f32_16x16x32_f16(a0, b, acc0[i], 0, 0, 0);
                acc1[i] = __builtin_amdgcn_mfma_f32_16x16x32_f16(a1, b, acc1[i], 0, 0, 0);
            }
        }
    }
}

// gather lat_in -> Ah cols 0..159 (f16), compute s_cut
__device__ __forceinline__ void gather_latin(
    const float* __restrict__ nodeinv, const float* __restrict__ edgeinv,
    const float* __restrict__ elen, const int* __restrict__ eidx,
    int e0, int t, _Float16* Ah, float* s_cut) {
    if (t < EB) s_cut[t] = cutf(elen[e0 + t]);
    for (int i = t; i < EB * 160; i += 256) {
        int ee = i / 160, k = i - ee * 160;
        int e = e0 + ee;
        float v;
        if (k < 64)       v = nodeinv[eidx[e] * 64 + k];
        else if (k < 128) v = nodeinv[eidx[NE + e] * 64 + (k - 64)];
        else if (k < 136) v = edgeinv[(size_t)e * 8 + (k - 128)];
        else              v = 0.f;
        Ah[ee * AST + k] = (_Float16)v;
    }
}

// lat0 (2 GEMMs) -> Ah cols 0..255 f16
__device__ __forceinline__ void lat0_mfma2(const _Float16* __restrict__ W2aT,
                                           const _Float16* __restrict__ W2bT,
                                           int t, _Float16* Ah, _Float16* AhB,
                                           const float* s_cut) {
    int wave = t >> 6, lane = t & 63, r = lane & 15, g = lane >> 4;
    f32x4 acc0[4], acc1[4];
    mfma_gemm2<16>(5, Ah, AST, W2aT, t, acc0, acc1);
#pragma unroll
    for (int i = 0; i < 4; ++i) {
        int nt = wave + 4 * i;
#pragma unroll
        for (int i2 = 0; i2 < 4; ++i2) {
            AhB[(g * 4 + i2) * BST + nt * 16 + r] = (_Float16)silu(acc0[i][i2]);
            AhB[(16 + g * 4 + i2) * BST + nt * 16 + r] = (_Float16)silu(acc1[i][i2]);
        }
    }
    __syncthreads();
    mfma_gemm2<16>(8, AhB, BST, W2bT, t, acc0, acc1);
#pragma unroll
    for (int i = 0; i < 4; ++i) {
        int nt = wave + 4 * i;
#pragma unroll
        for (int i2 = 0; i2 < 4; ++i2) {
            int ro = g * 4 + i2, col = nt * 16 + r;
            Ah[ro * AST + col] = (_Float16)(s_cut[ro] * silu(acc0[i][i2]));
            Ah[(16 + ro) * AST + col] = (_Float16)(s_cut[16 + ro] * silu(acc1[i][i2]));
        }
    }
    __syncthreads();
}

// lnorm(featN[center]) -> Ah cols 256..351 f16
__device__ __forceinline__ void gather_lnorm(const float* __restrict__ featN,
                                             const int* __restrict__ eidx,
                                             int e0, int t, _Float16* Ah) {
    for (int i = t; i < EB * 96; i += 256) {
        int ee = i / 96, rem = i - ee * 96;
        int l = rem >> 5, kk = rem & 31;
        int off = (l == 0) ? 0 : ((l == 1) ? 1 : 4);
        int d = (l == 0) ? 1 : ((l == 1) ? 3 : 5);
        const float* f = featN + (size_t)eidx[e0 + ee] * 288 + kk;
        float s = 1e-8f;
        for (int mm = off; mm < off + d; ++mm) { float x = f[mm * 32]; s = fmaf(x, x, s); }
        Ah[ee * AST + 256 + rem] = (_Float16)sqrtf(s);
    }
}

// scatter env += weight_channels(sh, s_w)*cut  (s_w f32 [EB][96])
__device__ __forceinline__ void scatter_env(const float* __restrict__ edge_attr,
                                            const int* __restrict__ eidx,
                                            const float* s_w, const float* s_cut,
                                            int e0, int t, float* __restrict__ env) {
    for (int i = t; i < EB * 32; i += 256) {
        int el = i >> 5, k = i & 31;
        int e = e0 + el;
        float cw = s_cut[el];
        int n = eidx[e];
        float w0 = s_w[el * 96 + k * 3 + 0] * cw;
        float w1 = s_w[el * 96 + k * 3 + 1] * cw;
        float w2 = s_w[el * 96 + k * 3 + 2] * cw;
        float* dst = env + (size_t)n * 288 + k;
#pragma unroll
        for (int m = 0; m < 9; ++m) {
            float w = (m == 0) ? w0 : ((m < 4) ? w1 : w2);
            atomicAdd(dst + m * 32, edge_attr[(size_t)e * 9 + m] * w);
        }
    }
}

// NT=6 epilogue -> s_w (f32) helper indices shared by k1/k3
__device__ __forceinline__ void epi6_f32(const f32x4* acc0, const f32x4* acc1, int t,
                                         float* s_w) {
    int wave = t >> 6, lane = t & 63, r = lane & 15, g = lane >> 4;
#pragma unroll
    for (int i = 0; i < 2; ++i) {
        int nt = wave + 4 * i;
        if (nt < 6) {
#pragma unroll
            for (int i2 = 0; i2 < 4; ++i2) {
                s_w[(g * 4 + i2) * 96 + nt * 16 + r] = acc0[i][i2];
                s_w[(16 + g * 4 + i2) * 96 + nt * 16 + r] = acc1[i][i2];
            }
        }
    }
}

// ---------------------------------------------------------------- K1: lat0 + (lat0@Wenv0b) + scatter
__global__ __launch_bounds__(256) void k1_lat_scatter0(
    const float* __restrict__ nodeinv, const float* __restrict__ edgeinv,
    const float* __restrict__ elen, const float* __restrict__ edge_attr,
    const int* __restrict__ eidx, const _Float16* __restrict__ W2aT,
    const _Float16* __restrict__ W2bT, const _Float16* __restrict__ Wenv0bT,
    float* __restrict__ env) {
    __shared__ alignas(16) _Float16 Ah[EB * AST];
    __shared__ alignas(16) _Float16 AhB[EB * BST];
    __shared__ float s_cut[EB];
    float* s_w = (float*)AhB;  // overlay: AhB dead after lat0
    int t = threadIdx.x;
    int e0 = blockIdx.x * EB;
    gather_latin(nodeinv, edgeinv, elen, eidx, e0, t, Ah, s_cut);
    __syncthreads();
    lat0_mfma2(W2aT, W2bT, t, Ah, AhB, s_cut);
    f32x4 acc0[4], acc1[4];
    mfma_gemm2<6>(8, Ah, AST, Wenv0bT, t, acc0, acc1);
    epi6_f32(acc0, acc1, t, s_w);
    __syncthreads();
    scatter_env(edge_attr, eidx, s_w, s_cut, e0, t, env);
}

// ---------------------------------------------------------------- node transform (unchanged)
__global__ __launch_bounds__(288) void k_node(
    const float* envin, const float* __restrict__ nodeinv,
    const float* __restrict__ Wenvlin, const float* __restrict__ Wprod,
    const float* __restrict__ Wfeat, float* featOut) {
    __shared__ float s_env[288];
    __shared__ float s_inv[64];
    __shared__ float s_mix[288];
    __shared__ float s_ew[96];
    int n = blockIdx.x;
    int t = threadIdx.x;
    s_env[t] = envin[(size_t)n * 288 + t] * (1.0f / 32.0f);
    if (t < 64) s_inv[t] = nodeinv[n * 64 + t];
    __syncthreads();
    int m = t >> 5, j = t & 31;
    int l = (m == 0) ? 0 : ((m < 4) ? 1 : 2);
    float a = 0.f;
    for (int k = 0; k < 32; ++k) a = fmaf(s_env[m * 32 + k], Wenvlin[l * 1024 + k * 32 + j], a);
    if (t < 96) {
        int c = t >> 5, jj = t & 31;
        float b = 0.f;
        for (int tt = 0; tt < 64; ++tt) b = fmaf(s_inv[tt], Wprod[c * 2048 + tt * 32 + jj], b);
        s_ew[t] = b;
    }
    s_mix[t] = a;
    __syncthreads();
    float s = s_mix[j];
    float p = s_mix[t] * (s_ew[j] + s_ew[32 + j] * s + s_ew[64 + j] * s * s);
    __syncthreads();
    s_env[t] = p;
    __syncthreads();
    float o = 0.f;
    for (int jl = 0; jl < 32; ++jl) o = fmaf(s_env[m * 32 + jl], Wfeat[l * 1024 + jl * 32 + j], o);
    featOut[(size_t)n * 288 + t] = o;
}

// ---------------------------------------------------------------- K3: lat0 -> lat1 -> (lat1@Wenv1) + scatter
__global__ __launch_bounds__(256) void k3_update_scatter1(
    const float* __restrict__ nodeinv, const float* __restrict__ edgeinv,
    const float* __restrict__ elen, const float* __restrict__ edge_attr,
    const int* __restrict__ eidx, const _Float16* __restrict__ W2aT,
    const _Float16* __restrict__ W2bT, const _Float16* __restrict__ Wl1aT,
    const _Float16* __restrict__ Wl1bT, const _Float16* __restrict__ Wenv1T,
    const float* __restrict__ featN0, float* __restrict__ env) {
    __shared__ alignas(16) _Float16 Ah[EB * AST];
    __shared__ alignas(16) _Float16 AhB[EB * BST];
    __shared__ float s_cut[EB];
    float* s_w = (float*)AhB;
    int t = threadIdx.x;
    int e0 = blockIdx.x * EB;
    int wave = t >> 6, lane = t & 63, r = lane & 15, g = lane >> 4;
    gather_latin(nodeinv, edgeinv, elen, eidx, e0, t, Ah, s_cut);
    gather_lnorm(featN0, eidx, e0, t, Ah);
    __syncthreads();
    lat0_mfma2(W2aT, W2bT, t, Ah, AhB, s_cut);
    f32x4 acc0[4], acc1[4];
    mfma_gemm2<16>(11, Ah, AST, Wl1aT, t, acc0, acc1);
#pragma unroll
    for (int i = 0; i < 4; ++i) {
        int nt = wave + 4 * i;
#pragma unroll
        for (int i2 = 0; i2 < 4; ++i2) {
            AhB[(g * 4 + i2) * BST + nt * 16 + r] = (_Float16)silu(acc0[i][i2]);
            AhB[(16 + g * 4 + i2) * BST + nt * 16 + r] = (_Float16)silu(acc1[i][i2]);
        }
    }
    __syncthreads();
    mfma_gemm2<16>(8, AhB, BST, Wl1bT, t, acc0, acc1);
#pragma unroll
    for (int i = 0; i < 4; ++i) {
        int nt = wave + 4 * i;
#pragma unroll
        for (int i2 = 0; i2 < 4; ++i2) {
            int ro = g * 4 + i2, col = nt * 16 + r;
            float v0 = 0.8944271909999159f * (float)Ah[ro * AST + col] +
                       0.4472135954999579f * s_cut[ro] * silu(acc0[i][i2]);
            Ah[ro * AST + col] = (_Float16)v0;
            float v1 = 0.8944271909999159f * (float)Ah[(16 + ro) * AST + col] +
                       0.4472135954999579f * s_cut[16 + ro] * silu(acc1[i][i2]);
            Ah[(16 + ro) * AST + col] = (_Float16)v1;
        }
    }
    __syncthreads();
    mfma_gemm2<6>(8, Ah, AST, Wenv1T, t, acc0, acc1);
    epi6_f32(acc0, acc1, t, s_w);
    __syncthreads();
    scatter_env(edge_attr, eidx, s_w, s_cut, e0, t, env);
}

// ---------------------------------------------------------------- K5: lat0 -> w0, lat1; S; Wfin contraction; readout
__global__ __launch_bounds__(256) void k5_final(
    const float* __restrict__ nodeinv, const float* __restrict__ edgeinv,
    const float* __restrict__ elen, const float* __restrict__ edge_attr,
    const int* __restrict__ eidx, const _Float16* __restrict__ W2aT,
    const _Float16* __restrict__ W2bT, const _Float16* __restrict__ Wenv0aT,
    const _Float16* __restrict__ Wl1aT, const _Float16* __restrict__ Wl1bT,
    const _Float16* __restrict__ Bfin, const _Float16* __restrict__ Wro1T,
    const float* __restrict__ Wro2, const float* __restrict__ featN0,
    const float* __restrict__ featN1, float* __restrict__ out) {
    __shared__ alignas(16) _Float16 Ah[EB * AST];
    __shared__ alignas(16) _Float16 AhB[EB * BST];
    __shared__ alignas(16) _Float16 s_w0h[EB * 96];
    __shared__ float s_cut[EB];
    __shared__ float s_ps[EB][4];
    float* s_S = (float*)AhB;  // overlay after Wl1b
    int t = threadIdx.x;
    int e0 = blockIdx.x * EB;
    int wave = t >> 6, lane = t & 63, r = lane & 15, g = lane >> 4;
    gather_latin(nodeinv, edgeinv, elen, eidx, e0, t, Ah, s_cut);
    gather_lnorm(featN0, eidx, e0, t, Ah);
    __syncthreads();
    lat0_mfma2(W2aT, W2bT, t, Ah, AhB, s_cut);
    f32x4 acc0[4], acc1[4];
    // w0 = lat0 @ Wenv0[:,0:96] -> f16
    mfma_gemm2<6>(8, Ah, AST, Wenv0aT, t, acc0, acc1);
#pragma unroll
    for (int i = 0; i < 2; ++i) {
        int nt = wave + 4 * i;
        if (nt < 6) {
#pragma unroll
            for (int i2 = 0; i2 < 4; ++i2) {
                s_w0h[(g * 4 + i2) * 96 + nt * 16 + r] = (_Float16)acc0[i][i2];
                s_w0h[(16 + g * 4 + i2) * 96 + nt * 16 + r] = (_Float16)acc1[i][i2];
            }
        }
    }
    // lat1
    mfma_gemm2<16>(11, Ah, AST, Wl1aT, t, acc0, acc1);
#pragma unroll
    for (int i = 0; i < 4; ++i) {
        int nt = wave + 4 * i;
#pragma unroll
        for (int i2 = 0; i2 < 4; ++i2) {
            AhB[(g * 4 + i2) * BST + nt * 16 + r] = (_Float16)silu(acc0[i][i2]);
            AhB[(16 + g * 4 + i2) * BST + nt * 16 + r] = (_Float16)silu(acc1[i][i2]);
        }
    }
    __syncthreads();
    mfma_gemm2<16>(8, AhB, BST, Wl1bT, t, acc0, acc1);
#pragma unroll
    for (int i = 0; i < 4; ++i) {
        int nt = wave + 4 * i;
#pragma unroll
        for (int i2 = 0; i2 < 4; ++i2) {
            int ro = g * 4 + i2, col = nt * 16 + r;
            float v0 = 0.8944271909999159f * (float)Ah[ro * AST + col] +
                       0.4472135954999579f * s_cut[ro] * silu(acc0[i][i2]);
            Ah[ro * AST + col] = (_Float16)v0;
            float v1 = 0.8944271909999159f * (float)Ah[(16 + ro) * AST + col] +
                       0.4472135954999579f * s_cut[16 + ro] * silu(acc1[i][i2]);
            Ah[(16 + ro) * AST + col] = (_Float16)v1;
        }
    }
    __syncthreads();  // all AhB reads done; lat1 final in Ah
    // S[e,l,k] = sum_m featN1[center,m,k]*sh[e,m]  (into AhB overlay)
    for (int i = t; i < EB * 96; i += 256) {
        int ee = i / 96, rem = i - ee * 96;
        int l = rem >> 5, kk = rem & 31;
        int off = (l == 0) ? 0 : ((l == 1) ? 1 : 4);
        int d = (l == 0) ? 1 : ((l == 1) ? 3 : 5);
        int e = e0 + ee;
        const float* f = featN1 + (size_t)eidx[e] * 288 + kk;
        float s = 0.f;
        for (int mm = off; mm < off + d; ++mm)
            s = fmaf(f[mm * 32], edge_attr[(size_t)e * 9 + mm], s);
        s_S[ee * 96 + rem] = s;
    }
    __syncthreads();
    // ---- Wfin contraction: frag-major coalesced B, 2 m-tiles
    {
        int n15 = lane & 15, g8 = lane >> 4, mb = g8 * 4;
        f16x8 a0[8], a1[8];
#pragma unroll
        for (int cc = 0; cc < 8; ++cc) {
            a0[cc] = *(const f16x8*)(Ah + n15 * AST + cc * 32 + g8 * 8);
            a1[cc] = *(const f16x8*)(Ah + (16 + n15) * AST + cc * 32 + g8 * 8);
        }
        int ncombo = (wave < 2) ? 2 : 1;
        for (int ci = 0; ci < ncombo; ++ci) {
            int combo = wave + ci * 4;
            int l = combo >> 1, j0 = (combo & 1) * 16;
            f32x4 run0 = {0.f, 0.f, 0.f, 0.f}, run1 = {0.f, 0.f, 0.f, 0.f};
            for (int ke = 0; ke < 32; ++ke) {
                const _Float16* bb = Bfin + (size_t)(combo * 32 + ke) * 4096 + lane * 8;
                f32x4 ac0 = {0.f, 0.f, 0.f, 0.f}, ac1 = {0.f, 0.f, 0.f, 0.f};
#pragma unroll
                for (int cc = 0; cc < 8; ++cc) {
                    f16x8 b = *(const f16x8*)(bb + cc * 512);
                    ac0 = __builtin_amdgcn_mfma_f32_16x16x32_f16(a0[cc], b, ac0, 0, 0, 0);
                    ac1 = __builtin_amdgcn_mfma_f32_16x16x32_f16(a1[cc], b, ac1, 0, 0, 0);
                }
#pragma unroll
                for (int i2 = 0; i2 < 4; ++i2) {
                    run0[i2] = fmaf(ac0[i2], s_S[(mb + i2) * 96 + l * 32 + ke], run0[i2]);
                    run1[i2] = fmaf(ac1[i2], s_S[(16 + mb + i2) * 96 + l * 32 + ke], run1[i2]);
                }
            }
#pragma unroll
            for (int i2 = 0; i2 < 4; ++i2) {
                int jo = j0 + n15;
                Ah[(mb + i2) * AST + 256 + l * 32 + jo] =
                    (_Float16)((float)s_w0h[(mb + i2) * 96 + jo * 3 + l] * run0[i2]);
                Ah[(16 + mb + i2) * AST + 256 + l * 32 + jo] =
                    (_Float16)((float)s_w0h[(16 + mb + i2) * 96 + jo * 3 + l] * run1[i2]);
            }
        }
    }
    __syncthreads();
    // readout GEMM + row-sum
    mfma_gemm2<16>(11, Ah, AST, Wro1T, t, acc0, acc1);
    float v0[4] = {0.f, 0.f, 0.f, 0.f}, v1[4] = {0.f, 0.f, 0.f, 0.f};
#pragma unroll
    for (int i = 0; i < 4; ++i) {
        int col = (wave + 4 * i) * 16 + r;
        float w2 = Wro2[col];
#pragma unroll
        for (int i2 = 0; i2 < 4; ++i2) {
            v0[i2] += silu(acc0[i][i2]) * w2;
            v1[i2] += silu(acc1[i][i2]) * w2;
        }
    }
#pragma unroll
    for (int off = 1; off < 16; off <<= 1) {
#pragma unroll
        for (int i2 = 0; i2 < 4; ++i2) {
            v0[i2] += __shfl_xor(v0[i2], off);
            v1[i2] += __shfl_xor(v1[i2], off);
        }
    }
    if (r == 0) {
#pragma unroll
        for (int i2 = 0; i2 < 4; ++i2) {
            s_ps[g * 4 + i2][wave] = v0[i2];
            s_ps[16 + g * 4 + i2][wave] = v1[i2];
        }
    }
    __syncthreads();
    if (t < EB) out[e0 + t] = s_ps[t][0] + s_ps[t][1] + s_ps[t][2] + s_ps[t][3];
}

// ----------------------------------------------------------------
extern "C" void kernel_launch(void* const* d_in, const int* in_sizes, int n_in,
                              void* d_out, int out_size, void* d_ws, size_t ws_size,
                              hipStream_t stream) {
    (void)in_sizes; (void)n_in; (void)out_size;
    const float* edge_attr = (const float*)d_in[0];
    const float* edge_len  = (const float*)d_in[1];
    const float* edge_inv  = (const float*)d_in[2];
    const float* node_inv  = (const float*)d_in[3];
    const float* W2a     = (const float*)d_in[4];
    const float* W2b     = (const float*)d_in[5];
    const float* Wl1a    = (const float*)d_in[6];
    const float* Wl1b    = (const float*)d_in[7];
    const float* Wenv0   = (const float*)d_in[8];
    const float* Wenv1   = (const float*)d_in[9];
    const float* Wenvlin = (const float*)d_in[10];
    const float* Wprod   = (const float*)d_in[11];
    const float* Wfeat   = (const float*)d_in[12];
    const float* Wfinlat = (const float*)d_in[13];
    const float* Wro1    = (const float*)d_in[14];
    const float* Wro2    = (const float*)d_in[15];
    const int* eidx      = (const int*)d_in[16];
    float* out = (float*)d_out;

    // ws: frag-major f16 weights (~2.42 MB) + env + featN0 (23.04 MB)
    _Float16* p = (_Float16*)d_ws;
    _Float16* Bfin    = p; p += 786432;   // 6*32*8*64*8
    _Float16* W2aT    = p; p += 40960;    // NT16 KS5
    _Float16* W2bT    = p; p += 65536;    // NT16 KS8
    _Float16* Wenv0aT = p; p += 24576;    // NT6 KS8
    _Float16* Wenv0bT = p; p += 24576;
    _Float16* Wenv1T  = p; p += 24576;
    _Float16* Wl1aT   = p; p += 90112;    // NT16 KS11
    _Float16* Wl1bT   = p; p += 65536;
    _Float16* Wro1T   = p; p += 90112;
    float* env    = (float*)p;
    float* featN0 = env + (size_t)NNODES * 288;
    size_t need = (size_t)((char*)(featN0 + (size_t)NNODES * 288) - (char*)d_ws);
    if (ws_size < need) return;  // absmax==0.318 signature => ws too small

    const int ENV_N = NNODES * 288;
    k_packfin<<<3072, 256, 0, stream>>>(Wfinlat, Bfin);
    k_packf<<<160, 256, 0, stream>>>(W2a, W2aT, 136, 5, 16, 256, 0);
    k_packf<<<256, 256, 0, stream>>>(W2b, W2bT, 256, 8, 16, 256, 0);
    k_packf<<<96, 256, 0, stream>>>(Wenv0, Wenv0aT, 256, 8, 6, 192, 0);
    k_packf<<<96, 256, 0, stream>>>(Wenv0, Wenv0bT, 256, 8, 6, 192, 96);
    k_packf<<<96, 256, 0, stream>>>(Wenv1, Wenv1T, 256, 8, 6, 96, 0);
    k_packf<<<352, 256, 0, stream>>>(Wl1a, Wl1aT, 352, 11, 16, 256, 0);
    k_packf<<<256, 256, 0, stream>>>(Wl1b, Wl1bT, 256, 8, 16, 256, 0);
    k_packf<<<352, 256, 0, stream>>>(Wro1, Wro1T, 352, 11, 16, 256, 0);

    k_zero<<<(ENV_N + 255) / 256, 256, 0, stream>>>(env, ENV_N);
    k1_lat_scatter0<<<NBLK, 256, 0, stream>>>(node_inv, edge_inv, edge_len, edge_attr,
                                              eidx, W2aT, W2bT, Wenv0bT, env);
    k_node<<<NNODES, 288, 0, stream>>>(env, node_inv, Wenvlin, Wprod, Wfeat, featN0);
    k_zero<<<(ENV_N + 255) / 256, 256, 0, stream>>>(env, ENV_N);
    k3_update_scatter1<<<NBLK, 256, 0, stream>>>(node_inv, edge_inv, edge_len, edge_attr,
                                                 eidx, W2aT, W2bT, Wl1aT, Wl1bT, Wenv1T,
                                                 featN0, env);
    k_node<<<NNODES, 288, 0, stream>>>(env, node_inv, Wenvlin + 3072, Wprod + 6144,
                                       Wfeat + 3072, env);  // in-place: env1 -> featN1
    k5_final<<<NBLK, 256, 0, stream>>>(node_inv, edge_inv, edge_len, edge_attr, eidx,
                                       W2aT, W2bT, Wenv0aT, Wl1aT, Wl1bT, Bfin, Wro1T,
                                       Wro2, featN0, env, out);
}

// Round 7
// 4890.396 us; speedup vs baseline: 5.1055x; 1.1458x over previous
//
#include <hip/hip_runtime.h>
#include <math.h>

#define NE 320000
#define NNODES 10000
#define EB 32
#define NBLK (NE / EB)
#define AST 360   // Ah stride (f16 elems)
#define BST 264   // AhB stride (f16 elems)

typedef _Float16 f16x8 __attribute__((ext_vector_type(8)));
typedef float f32x4 __attribute__((ext_vector_type(4)));

__device__ __forceinline__ float silu(float x) { return x / (1.0f + __expf(-x)); }
__device__ __forceinline__ float cutf(float len) {
    float x = len * (1.0f / 6.0f);
    float x2 = x * x, x6 = x2 * x2 * x2;
    float f = 1.0f - 28.0f * x6 + 48.0f * x6 * x - 21.0f * x6 * x2;
    return (x < 1.0f) ? f : 0.0f;
}

// ---------------------------------------------------------------- zero
__global__ __launch_bounds__(256) void k_zero(float* __restrict__ p, int n) {
    int i = blockIdx.x * 256 + threadIdx.x;
    if (i < n) p[i] = 0.f;
}

// ---------------------------------------------------------------- fragment-major pack for MLP weights
__global__ __launch_bounds__(256) void k_packf(const float* __restrict__ src,
                                               _Float16* __restrict__ dst,
                                               int K, int KS, int NT, int stride,
                                               int colOff) {
    int i = blockIdx.x * 256 + threadIdx.x;
    if (i >= NT * KS * 512) return;
    int j = i & 7, lane = (i >> 3) & 63;
    int blk = i >> 9;
    int ks = blk % KS, nt = blk / KS;
    int k = ks * 32 + (lane >> 4) * 8 + j;
    int n = colOff + nt * 16 + (lane & 15);
    dst[i] = (k < K) ? (_Float16)src[(size_t)k * stride + n] : (_Float16)0.f;
}

// ---------------------------------------------------------------- fragment-major pack of Wfinlat (contraction B)
__global__ __launch_bounds__(256) void k_packfin(const float* __restrict__ W,
                                                 _Float16* __restrict__ dst) {
    int i = blockIdx.x * 256 + threadIdx.x;  // < 786432
    int j = i & 7, lane = (i >> 3) & 63, cc = (i >> 9) & 7, ke = (i >> 12) & 31,
        combo = i >> 17;
    int n = (combo >> 1) * 1024 + ke * 32 + (combo & 1) * 16 + (lane & 15);
    int c = cc * 32 + (lane >> 4) * 8 + j;
    dst[i] = (_Float16)W[(size_t)c * 3072 + n];
}

// ---------------------------------------------------------------- MFMA GEMM, 32 edges (2 m-tiles), frag-major B
template <int NT>
__device__ __forceinline__ void mfma_gemm2(int ksteps, const _Float16* Ah, int astride,
                                           const _Float16* __restrict__ Wt, int t,
                                           f32x4* acc0, f32x4* acc1) {
    int wave = t >> 6, lane = t & 63, r = lane & 15, g = lane >> 4;
    const int TPW = (NT + 3) / 4;
#pragma unroll
    for (int i = 0; i < TPW; ++i) {
        acc0[i] = (f32x4){0.f, 0.f, 0.f, 0.f};
        acc1[i] = (f32x4){0.f, 0.f, 0.f, 0.f};
    }
    for (int ks = 0; ks < ksteps; ++ks) {
        f16x8 a0 = *(const f16x8*)(Ah + r * astride + ks * 32 + g * 8);
        f16x8 a1 = *(const f16x8*)(Ah + (16 + r) * astride + ks * 32 + g * 8);
#pragma unroll
        for (int i = 0; i < TPW; ++i) {
            int nt = wave + 4 * i;
            if (nt < NT) {
                f16x8 b = *(const f16x8*)(Wt + ((size_t)(nt * ksteps + ks) * 64 + lane) * 8);
                acc0[i] = __builtin_amdgcn_mfma_f32_16x16x32_f16(a0, b, acc0[i], 0, 0, 0);
                acc1[i] = __builtin_amdgcn_mfma_f32_16x16x32_f16(a1, b, acc1[i], 0, 0, 0);
            }
        }
    }
}

// gather lat_in -> Ah cols 0..159 (f16), compute s_cut
__device__ __forceinline__ void gather_latin(
    const float* __restrict__ nodeinv, const float* __restrict__ edgeinv,
    const float* __restrict__ elen, const int* __restrict__ eidx,
    int e0, int t, _Float16* Ah, float* s_cut) {
    if (t < EB) s_cut[t] = cutf(elen[e0 + t]);
    for (int i = t; i < EB * 160; i += 256) {
        int ee = i / 160, k = i - ee * 160;
        int e = e0 + ee;
        float v;
        if (k < 64)       v = nodeinv[eidx[e] * 64 + k];
        else if (k < 128) v = nodeinv[eidx[NE + e] * 64 + (k - 64)];
        else if (k < 136) v = edgeinv[(size_t)e * 8 + (k - 128)];
        else              v = 0.f;
        Ah[ee * AST + k] = (_Float16)v;
    }
}

// lat0 (2 GEMMs) -> Ah cols 0..255 f16
__device__ __forceinline__ void lat0_mfma2(const _Float16* __restrict__ W2aT,
                                           const _Float16* __restrict__ W2bT,
                                           int t, _Float16* Ah, _Float16* AhB,
                                           const float* s_cut) {
    int wave = t >> 6, lane = t & 63, r = lane & 15, g = lane >> 4;
    f32x4 acc0[4], acc1[4];
    mfma_gemm2<16>(5, Ah, AST, W2aT, t, acc0, acc1);
#pragma unroll
    for (int i = 0; i < 4; ++i) {
        int nt = wave + 4 * i;
#pragma unroll
        for (int i2 = 0; i2 < 4; ++i2) {
            AhB[(g * 4 + i2) * BST + nt * 16 + r] = (_Float16)silu(acc0[i][i2]);
            AhB[(16 + g * 4 + i2) * BST + nt * 16 + r] = (_Float16)silu(acc1[i][i2]);
        }
    }
    __syncthreads();
    mfma_gemm2<16>(8, AhB, BST, W2bT, t, acc0, acc1);
#pragma unroll
    for (int i = 0; i < 4; ++i) {
        int nt = wave + 4 * i;
#pragma unroll
        for (int i2 = 0; i2 < 4; ++i2) {
            int ro = g * 4 + i2, col = nt * 16 + r;
            Ah[ro * AST + col] = (_Float16)(s_cut[ro] * silu(acc0[i][i2]));
            Ah[(16 + ro) * AST + col] = (_Float16)(s_cut[16 + ro] * silu(acc1[i][i2]));
        }
    }
    __syncthreads();
}

// lnorm(featN[center]) -> Ah cols 256..351 f16
__device__ __forceinline__ void gather_lnorm(const float* __restrict__ featN,
                                             const int* __restrict__ eidx,
                                             int e0, int t, _Float16* Ah) {
    for (int i = t; i < EB * 96; i += 256) {
        int ee = i / 96, rem = i - ee * 96;
        int l = rem >> 5, kk = rem & 31;
        int off = (l == 0) ? 0 : ((l == 1) ? 1 : 4);
        int d = (l == 0) ? 1 : ((l == 1) ? 3 : 5);
        const float* f = featN + (size_t)eidx[e0 + ee] * 288 + kk;
        float s = 1e-8f;
        for (int mm = off; mm < off + d; ++mm) { float x = f[mm * 32]; s = fmaf(x, x, s); }
        Ah[ee * AST + 256 + rem] = (_Float16)sqrtf(s);
    }
}

// scatter env += weight_channels(sh, s_w)*cut  (s_w f32 [EB][96])
__device__ __forceinline__ void scatter_env(const float* __restrict__ edge_attr,
                                            const int* __restrict__ eidx,
                                            const float* s_w, const float* s_cut,
                                            int e0, int t, float* __restrict__ env) {
    for (int i = t; i < EB * 32; i += 256) {
        int el = i >> 5, k = i & 31;
        int e = e0 + el;
        float cw = s_cut[el];
        int n = eidx[e];
        float w0 = s_w[el * 96 + k * 3 + 0] * cw;
        float w1 = s_w[el * 96 + k * 3 + 1] * cw;
        float w2 = s_w[el * 96 + k * 3 + 2] * cw;
        float* dst = env + (size_t)n * 288 + k;
#pragma unroll
        for (int m = 0; m < 9; ++m) {
            float w = (m == 0) ? w0 : ((m < 4) ? w1 : w2);
            atomicAdd(dst + m * 32, edge_attr[(size_t)e * 9 + m] * w);
        }
    }
}

// NT=6 epilogue -> s_w (f32)
__device__ __forceinline__ void epi6_f32(const f32x4* acc0, const f32x4* acc1, int t,
                                         float* s_w) {
    int wave = t >> 6, lane = t & 63, r = lane & 15, g = lane >> 4;
#pragma unroll
    for (int i = 0; i < 2; ++i) {
        int nt = wave + 4 * i;
        if (nt < 6) {
#pragma unroll
            for (int i2 = 0; i2 < 4; ++i2) {
                s_w[(g * 4 + i2) * 96 + nt * 16 + r] = acc0[i][i2];
                s_w[(16 + g * 4 + i2) * 96 + nt * 16 + r] = acc1[i][i2];
            }
        }
    }
}

// ---------------------------------------------------------------- K1: lat0 + (lat0@Wenv0b) + scatter
__global__ __launch_bounds__(256) void k1_lat_scatter0(
    const float* __restrict__ nodeinv, const float* __restrict__ edgeinv,
    const float* __restrict__ elen, const float* __restrict__ edge_attr,
    const int* __restrict__ eidx, const _Float16* __restrict__ W2aT,
    const _Float16* __restrict__ W2bT, const _Float16* __restrict__ Wenv0bT,
    float* __restrict__ env) {
    __shared__ alignas(16) _Float16 Ah[EB * AST];
    __shared__ alignas(16) _Float16 AhB[EB * BST];
    __shared__ float s_cut[EB];
    float* s_w = (float*)AhB;  // overlay: AhB dead after lat0
    int t = threadIdx.x;
    int e0 = blockIdx.x * EB;
    gather_latin(nodeinv, edgeinv, elen, eidx, e0, t, Ah, s_cut);
    __syncthreads();
    lat0_mfma2(W2aT, W2bT, t, Ah, AhB, s_cut);
    f32x4 acc0[4], acc1[4];
    mfma_gemm2<6>(8, Ah, AST, Wenv0bT, t, acc0, acc1);
    epi6_f32(acc0, acc1, t, s_w);
    __syncthreads();
    scatter_env(edge_attr, eidx, s_w, s_cut, e0, t, env);
}

// ---------------------------------------------------------------- node transform (unchanged)
__global__ __launch_bounds__(288) void k_node(
    const float* envin, const float* __restrict__ nodeinv,
    const float* __restrict__ Wenvlin, const float* __restrict__ Wprod,
    const float* __restrict__ Wfeat, float* featOut) {
    __shared__ float s_env[288];
    __shared__ float s_inv[64];
    __shared__ float s_mix[288];
    __shared__ float s_ew[96];
    int n = blockIdx.x;
    int t = threadIdx.x;
    s_env[t] = envin[(size_t)n * 288 + t] * (1.0f / 32.0f);
    if (t < 64) s_inv[t] = nodeinv[n * 64 + t];
    __syncthreads();
    int m = t >> 5, j = t & 31;
    int l = (m == 0) ? 0 : ((m < 4) ? 1 : 2);
    float a = 0.f;
    for (int k = 0; k < 32; ++k) a = fmaf(s_env[m * 32 + k], Wenvlin[l * 1024 + k * 32 + j], a);
    if (t < 96) {
        int c = t >> 5, jj = t & 31;
        float b = 0.f;
        for (int tt = 0; tt < 64; ++tt) b = fmaf(s_inv[tt], Wprod[c * 2048 + tt * 32 + jj], b);
        s_ew[t] = b;
    }
    s_mix[t] = a;
    __syncthreads();
    float s = s_mix[j];
    float p = s_mix[t] * (s_ew[j] + s_ew[32 + j] * s + s_ew[64 + j] * s * s);
    __syncthreads();
    s_env[t] = p;
    __syncthreads();
    float o = 0.f;
    for (int jl = 0; jl < 32; ++jl) o = fmaf(s_env[m * 32 + jl], Wfeat[l * 1024 + jl * 32 + j], o);
    featOut[(size_t)n * 288 + t] = o;
}

// ---------------------------------------------------------------- K3: lat0 -> lat1 -> (lat1@Wenv1) + scatter [+ persist lat1h,w0h]
__global__ __launch_bounds__(256) void k3_update_scatter1(
    const float* __restrict__ nodeinv, const float* __restrict__ edgeinv,
    const float* __restrict__ elen, const float* __restrict__ edge_attr,
    const int* __restrict__ eidx, const _Float16* __restrict__ W2aT,
    const _Float16* __restrict__ W2bT, const _Float16* __restrict__ Wl1aT,
    const _Float16* __restrict__ Wl1bT, const _Float16* __restrict__ Wenv1T,
    const _Float16* __restrict__ Wenv0aT, const float* __restrict__ featN0,
    float* __restrict__ env, _Float16* __restrict__ lat1h,
    _Float16* __restrict__ w0h) {
    __shared__ alignas(16) _Float16 Ah[EB * AST];
    __shared__ alignas(16) _Float16 AhB[EB * BST];
    __shared__ float s_cut[EB];
    float* s_w = (float*)AhB;
    int t = threadIdx.x;
    int e0 = blockIdx.x * EB;
    int wave = t >> 6, lane = t & 63, r = lane & 15, g = lane >> 4;
    gather_latin(nodeinv, edgeinv, elen, eidx, e0, t, Ah, s_cut);
    gather_lnorm(featN0, eidx, e0, t, Ah);
    __syncthreads();
    lat0_mfma2(W2aT, W2bT, t, Ah, AhB, s_cut);
    f32x4 acc0[4], acc1[4];
    if (w0h) {  // w0 = lat0 @ Wenv0[:,0:96] (lat0 still in Ah)
        mfma_gemm2<6>(8, Ah, AST, Wenv0aT, t, acc0, acc1);
#pragma unroll
        for (int i = 0; i < 2; ++i) {
            int nt = wave + 4 * i;
            if (nt < 6) {
#pragma unroll
                for (int i2 = 0; i2 < 4; ++i2) {
                    w0h[(size_t)(e0 + g * 4 + i2) * 96 + nt * 16 + r] = (_Float16)acc0[i][i2];
                    w0h[(size_t)(e0 + 16 + g * 4 + i2) * 96 + nt * 16 + r] = (_Float16)acc1[i][i2];
                }
            }
        }
    }
    mfma_gemm2<16>(11, Ah, AST, Wl1aT, t, acc0, acc1);
#pragma unroll
    for (int i = 0; i < 4; ++i) {
        int nt = wave + 4 * i;
#pragma unroll
        for (int i2 = 0; i2 < 4; ++i2) {
            AhB[(g * 4 + i2) * BST + nt * 16 + r] = (_Float16)silu(acc0[i][i2]);
            AhB[(16 + g * 4 + i2) * BST + nt * 16 + r] = (_Float16)silu(acc1[i][i2]);
        }
    }
    __syncthreads();
    mfma_gemm2<16>(8, AhB, BST, Wl1bT, t, acc0, acc1);
#pragma unroll
    for (int i = 0; i < 4; ++i) {
        int nt = wave + 4 * i;
#pragma unroll
        for (int i2 = 0; i2 < 4; ++i2) {
            int ro = g * 4 + i2, col = nt * 16 + r;
            float v0 = 0.8944271909999159f * (float)Ah[ro * AST + col] +
                       0.4472135954999579f * s_cut[ro] * silu(acc0[i][i2]);
            _Float16 h0 = (_Float16)v0;
            Ah[ro * AST + col] = h0;
            float v1 = 0.8944271909999159f * (float)Ah[(16 + ro) * AST + col] +
                       0.4472135954999579f * s_cut[16 + ro] * silu(acc1[i][i2]);
            _Float16 h1 = (_Float16)v1;
            Ah[(16 + ro) * AST + col] = h1;
            if (lat1h) {
                lat1h[(size_t)(e0 + ro) * 256 + col] = h0;
                lat1h[(size_t)(e0 + 16 + ro) * 256 + col] = h1;
            }
        }
    }
    __syncthreads();
    mfma_gemm2<6>(8, Ah, AST, Wenv1T, t, acc0, acc1);
    epi6_f32(acc0, acc1, t, s_w);
    __syncthreads();
    scatter_env(edge_attr, eidx, s_w, s_cut, e0, t, env);
}

// ---------------------------------------------------------------- K5 slow (R6 verbatim): recompute path
__global__ __launch_bounds__(256) void k5_final(
    const float* __restrict__ nodeinv, const float* __restrict__ edgeinv,
    const float* __restrict__ elen, const float* __restrict__ edge_attr,
    const int* __restrict__ eidx, const _Float16* __restrict__ W2aT,
    const _Float16* __restrict__ W2bT, const _Float16* __restrict__ Wenv0aT,
    const _Float16* __restrict__ Wl1aT, const _Float16* __restrict__ Wl1bT,
    const _Float16* __restrict__ Bfin, const _Float16* __restrict__ Wro1T,
    const float* __restrict__ Wro2, const float* __restrict__ featN0,
    const float* __restrict__ featN1, float* __restrict__ out) {
    __shared__ alignas(16) _Float16 Ah[EB * AST];
    __shared__ alignas(16) _Float16 AhB[EB * BST];
    __shared__ alignas(16) _Float16 s_w0h[EB * 96];
    __shared__ float s_cut[EB];
    __shared__ float s_ps[EB][4];
    float* s_S = (float*)AhB;
    int t = threadIdx.x;
    int e0 = blockIdx.x * EB;
    int wave = t >> 6, lane = t & 63, r = lane & 15, g = lane >> 4;
    gather_latin(nodeinv, edgeinv, elen, eidx, e0, t, Ah, s_cut);
    gather_lnorm(featN0, eidx, e0, t, Ah);
    __syncthreads();
    lat0_mfma2(W2aT, W2bT, t, Ah, AhB, s_cut);
    f32x4 acc0[4], acc1[4];
    mfma_gemm2<6>(8, Ah, AST, Wenv0aT, t, acc0, acc1);
#pragma unroll
    for (int i = 0; i < 2; ++i) {
        int nt = wave + 4 * i;
        if (nt < 6) {
#pragma unroll
            for (int i2 = 0; i2 < 4; ++i2) {
                s_w0h[(g * 4 + i2) * 96 + nt * 16 + r] = (_Float16)acc0[i][i2];
                s_w0h[(16 + g * 4 + i2) * 96 + nt * 16 + r] = (_Float16)acc1[i][i2];
            }
        }
    }
    mfma_gemm2<16>(11, Ah, AST, Wl1aT, t, acc0, acc1);
#pragma unroll
    for (int i = 0; i < 4; ++i) {
        int nt = wave + 4 * i;
#pragma unroll
        for (int i2 = 0; i2 < 4; ++i2) {
            AhB[(g * 4 + i2) * BST + nt * 16 + r] = (_Float16)silu(acc0[i][i2]);
            AhB[(16 + g * 4 + i2) * BST + nt * 16 + r] = (_Float16)silu(acc1[i][i2]);
        }
    }
    __syncthreads();
    mfma_gemm2<16>(8, AhB, BST, Wl1bT, t, acc0, acc1);
#pragma unroll
    for (int i = 0; i < 4; ++i) {
        int nt = wave + 4 * i;
#pragma unroll
        for (int i2 = 0; i2 < 4; ++i2) {
            int ro = g * 4 + i2, col = nt * 16 + r;
            float v0 = 0.8944271909999159f * (float)Ah[ro * AST + col] +
                       0.4472135954999579f * s_cut[ro] * silu(acc0[i][i2]);
            Ah[ro * AST + col] = (_Float16)v0;
            float v1 = 0.8944271909999159f * (float)Ah[(16 + ro) * AST + col] +
                       0.4472135954999579f * s_cut[16 + ro] * silu(acc1[i][i2]);
            Ah[(16 + ro) * AST + col] = (_Float16)v1;
        }
    }
    __syncthreads();
    for (int i = t; i < EB * 96; i += 256) {
        int ee = i / 96, rem = i - ee * 96;
        int l = rem >> 5, kk = rem & 31;
        int off = (l == 0) ? 0 : ((l == 1) ? 1 : 4);
        int d = (l == 0) ? 1 : ((l == 1) ? 3 : 5);
        int e = e0 + ee;
        const float* f = featN1 + (size_t)eidx[e] * 288 + kk;
        float s = 0.f;
        for (int mm = off; mm < off + d; ++mm)
            s = fmaf(f[mm * 32], edge_attr[(size_t)e * 9 + mm], s);
        s_S[ee * 96 + rem] = s;
    }
    __syncthreads();
    {
        int n15 = lane & 15, g8 = lane >> 4, mb = g8 * 4;
        f16x8 a0[8], a1[8];
#pragma unroll
        for (int cc = 0; cc < 8; ++cc) {
            a0[cc] = *(const f16x8*)(Ah + n15 * AST + cc * 32 + g8 * 8);
            a1[cc] = *(const f16x8*)(Ah + (16 + n15) * AST + cc * 32 + g8 * 8);
        }
        int ncombo = (wave < 2) ? 2 : 1;
        for (int ci = 0; ci < ncombo; ++ci) {
            int combo = wave + ci * 4;
            int l = combo >> 1, j0 = (combo & 1) * 16;
            f32x4 run0 = {0.f, 0.f, 0.f, 0.f}, run1 = {0.f, 0.f, 0.f, 0.f};
            for (int ke = 0; ke < 32; ++ke) {
                const _Float16* bb = Bfin + (size_t)(combo * 32 + ke) * 4096 + lane * 8;
                f32x4 ac0 = {0.f, 0.f, 0.f, 0.f}, ac1 = {0.f, 0.f, 0.f, 0.f};
#pragma unroll
                for (int cc = 0; cc < 8; ++cc) {
                    f16x8 b = *(const f16x8*)(bb + cc * 512);
                    ac0 = __builtin_amdgcn_mfma_f32_16x16x32_f16(a0[cc], b, ac0, 0, 0, 0);
                    ac1 = __builtin_amdgcn_mfma_f32_16x16x32_f16(a1[cc], b, ac1, 0, 0, 0);
                }
#pragma unroll
                for (int i2 = 0; i2 < 4; ++i2) {
                    run0[i2] = fmaf(ac0[i2], s_S[(mb + i2) * 96 + l * 32 + ke], run0[i2]);
                    run1[i2] = fmaf(ac1[i2], s_S[(16 + mb + i2) * 96 + l * 32 + ke], run1[i2]);
                }
            }
#pragma unroll
            for (int i2 = 0; i2 < 4; ++i2) {
                int jo = j0 + n15;
                Ah[(mb + i2) * AST + 256 + l * 32 + jo] =
                    (_Float16)((float)s_w0h[(mb + i2) * 96 + jo * 3 + l] * run0[i2]);
                Ah[(16 + mb + i2) * AST + 256 + l * 32 + jo] =
                    (_Float16)((float)s_w0h[(16 + mb + i2) * 96 + jo * 3 + l] * run1[i2]);
            }
        }
    }
    __syncthreads();
    mfma_gemm2<16>(11, Ah, AST, Wro1T, t, acc0, acc1);
    float v0[4] = {0.f, 0.f, 0.f, 0.f}, v1[4] = {0.f, 0.f, 0.f, 0.f};
#pragma unroll
    for (int i = 0; i < 4; ++i) {
        int col = (wave + 4 * i) * 16 + r;
        float w2 = Wro2[col];
#pragma unroll
        for (int i2 = 0; i2 < 4; ++i2) {
            v0[i2] += silu(acc0[i][i2]) * w2;
            v1[i2] += silu(acc1[i][i2]) * w2;
        }
    }
#pragma unroll
    for (int off = 1; off < 16; off <<= 1) {
#pragma unroll
        for (int i2 = 0; i2 < 4; ++i2) {
            v0[i2] += __shfl_xor(v0[i2], off);
            v1[i2] += __shfl_xor(v1[i2], off);
        }
    }
    if (r == 0) {
#pragma unroll
        for (int i2 = 0; i2 < 4; ++i2) {
            s_ps[g * 4 + i2][wave] = v0[i2];
            s_ps[16 + g * 4 + i2][wave] = v1[i2];
        }
    }
    __syncthreads();
    if (t < EB) out[e0 + t] = s_ps[t][0] + s_ps[t][1] + s_ps[t][2] + s_ps[t][3];
}

// ---------------------------------------------------------------- K5 fast: EB=64, no MLP recompute (lat1h, w0h persisted)
#define FEB 64
__global__ __launch_bounds__(256) void k5_fast(
    const float* __restrict__ edge_attr, const int* __restrict__ eidx,
    const _Float16* __restrict__ lat1h, const _Float16* __restrict__ w0h,
    const _Float16* __restrict__ Bfin, const _Float16* __restrict__ Wro1T,
    const float* __restrict__ Wro2, const float* __restrict__ featN1,
    float* __restrict__ out) {
    __shared__ alignas(16) _Float16 s_S[FEB * 96];  // S (f16), later scal-f16
    __shared__ float s_scal[FEB * 96];
    __shared__ float s_ps[FEB][4];
    int t = threadIdx.x;
    int e0 = blockIdx.x * FEB;
    int wave = t >> 6, lane = t & 63, r = lane & 15, g8 = lane >> 4;
    for (int i = t; i < FEB * 96; i += 256) s_scal[i] = 0.f;
    // S[e,l,k]
    for (int i = t; i < FEB * 96; i += 256) {
        int ee = i / 96, rem = i - ee * 96;
        int l = rem >> 5, kk = rem & 31;
        int off = (l == 0) ? 0 : ((l == 1) ? 1 : 4);
        int d = (l == 0) ? 1 : ((l == 1) ? 3 : 5);
        int e = e0 + ee;
        const float* f = featN1 + (size_t)eidx[e] * 288 + kk;
        float s = 0.f;
        for (int mm = off; mm < off + d; ++mm)
            s = fmaf(f[mm * 32], edge_attr[(size_t)e * 9 + mm], s);
        s_S[i] = (_Float16)s;
    }
    // A-frags (lat1) from global, reused by contraction AND readout
    f16x8 a[4][8];
#pragma unroll
    for (int mt = 0; mt < 4; ++mt)
#pragma unroll
        for (int cc = 0; cc < 8; ++cc)
            a[mt][cc] = *(const f16x8*)(lat1h + (size_t)(e0 + mt * 16 + r) * 256 +
                                        cc * 32 + g8 * 8);
    __syncthreads();
    // 12 balanced units: (combo, ke-half)
    for (int ui = 0; ui < 3; ++ui) {
        int u = wave + 4 * ui;
        int combo = u >> 1, kh = u & 1;
        int l = combo >> 1, j0 = (combo & 1) * 16;
        f32x4 run[4];
#pragma unroll
        for (int mt = 0; mt < 4; ++mt) run[mt] = (f32x4){0.f, 0.f, 0.f, 0.f};
        for (int kei = 0; kei < 16; ++kei) {
            int ke = kh * 16 + kei;
            const _Float16* bb = Bfin + (size_t)(combo * 32 + ke) * 4096 + lane * 8;
            f32x4 ac[4];
#pragma unroll
            for (int mt = 0; mt < 4; ++mt) ac[mt] = (f32x4){0.f, 0.f, 0.f, 0.f};
#pragma unroll
            for (int cc = 0; cc < 8; ++cc) {
                f16x8 b = *(const f16x8*)(bb + cc * 512);
#pragma unroll
                for (int mt = 0; mt < 4; ++mt)
                    ac[mt] = __builtin_amdgcn_mfma_f32_16x16x32_f16(a[mt][cc], b, ac[mt], 0, 0, 0);
            }
#pragma unroll
            for (int mt = 0; mt < 4; ++mt)
#pragma unroll
                for (int i2 = 0; i2 < 4; ++i2)
                    run[mt][i2] = fmaf(ac[mt][i2],
                                       (float)s_S[(mt * 16 + g8 * 4 + i2) * 96 + l * 32 + ke],
                                       run[mt][i2]);
        }
#pragma unroll
        for (int mt = 0; mt < 4; ++mt)
#pragma unroll
            for (int i2 = 0; i2 < 4; ++i2)
                atomicAdd(&s_scal[(mt * 16 + g8 * 4 + i2) * 96 + l * 32 + j0 + r],
                          run[mt][i2]);
    }
    __syncthreads();
    // apply w0, produce scal-f16 into s_S (dead)
    for (int i = t; i < FEB * 96; i += 256) {
        int m = i / 96, rem = i - m * 96;
        int l = rem >> 5, jo = rem & 31;
        float w0 = (float)w0h[(size_t)(e0 + m) * 96 + jo * 3 + l];
        s_S[i] = (_Float16)(s_scal[i] * w0);
    }
    __syncthreads();
    // readout: A cols 0..255 from regs (a), 256..351 from s_S
    f32x4 racc[4][4];
#pragma unroll
    for (int i = 0; i < 4; ++i)
#pragma unroll
        for (int mt = 0; mt < 4; ++mt) racc[i][mt] = (f32x4){0.f, 0.f, 0.f, 0.f};
    for (int ks = 0; ks < 11; ++ks) {
        f16x8 af[4];
#pragma unroll
        for (int mt = 0; mt < 4; ++mt)
            af[mt] = (ks < 8) ? a[mt][ks]
                              : *(const f16x8*)(s_S + (mt * 16 + r) * 96 + (ks - 8) * 32 + g8 * 8);
#pragma unroll
        for (int i = 0; i < 4; ++i) {
            int nt = wave + 4 * i;
            f16x8 b = *(const f16x8*)(Wro1T + ((size_t)(nt * 11 + ks) * 64 + lane) * 8);
#pragma unroll
            for (int mt = 0; mt < 4; ++mt)
                racc[i][mt] = __builtin_amdgcn_mfma_f32_16x16x32_f16(af[mt], b, racc[i][mt], 0, 0, 0);
        }
    }
    float v[4][4];
#pragma unroll
    for (int mt = 0; mt < 4; ++mt)
#pragma unroll
        for (int i2 = 0; i2 < 4; ++i2) v[mt][i2] = 0.f;
#pragma unroll
    for (int i = 0; i < 4; ++i) {
        int col = (wave + 4 * i) * 16 + r;
        float w2 = Wro2[col];
#pragma unroll
        for (int mt = 0; mt < 4; ++mt)
#pragma unroll
            for (int i2 = 0; i2 < 4; ++i2) v[mt][i2] += silu(racc[i][mt][i2]) * w2;
    }
#pragma unroll
    for (int off = 1; off < 16; off <<= 1)
#pragma unroll
        for (int mt = 0; mt < 4; ++mt)
#pragma unroll
            for (int i2 = 0; i2 < 4; ++i2) v[mt][i2] += __shfl_xor(v[mt][i2], off);
    if (r == 0) {
#pragma unroll
        for (int mt = 0; mt < 4; ++mt)
#pragma unroll
            for (int i2 = 0; i2 < 4; ++i2)
                s_ps[mt * 16 + g8 * 4 + i2][wave] = v[mt][i2];
    }
    __syncthreads();
    if (t < FEB) out[e0 + t] = s_ps[t][0] + s_ps[t][1] + s_ps[t][2] + s_ps[t][3];
}

// ----------------------------------------------------------------
extern "C" void kernel_launch(void* const* d_in, const int* in_sizes, int n_in,
                              void* d_out, int out_size, void* d_ws, size_t ws_size,
                              hipStream_t stream) {
    (void)in_sizes; (void)n_in; (void)out_size;
    const float* edge_attr = (const float*)d_in[0];
    const float* edge_len  = (const float*)d_in[1];
    const float* edge_inv  = (const float*)d_in[2];
    const float* node_inv  = (const float*)d_in[3];
    const float* W2a     = (const float*)d_in[4];
    const float* W2b     = (const float*)d_in[5];
    const float* Wl1a    = (const float*)d_in[6];
    const float* Wl1b    = (const float*)d_in[7];
    const float* Wenv0   = (const float*)d_in[8];
    const float* Wenv1   = (const float*)d_in[9];
    const float* Wenvlin = (const float*)d_in[10];
    const float* Wprod   = (const float*)d_in[11];
    const float* Wfeat   = (const float*)d_in[12];
    const float* Wfinlat = (const float*)d_in[13];
    const float* Wro1    = (const float*)d_in[14];
    const float* Wro2    = (const float*)d_in[15];
    const int* eidx      = (const int*)d_in[16];
    float* out = (float*)d_out;

    _Float16* p = (_Float16*)d_ws;
    _Float16* Bfin    = p; p += 786432;
    _Float16* W2aT    = p; p += 40960;
    _Float16* W2bT    = p; p += 65536;
    _Float16* Wenv0aT = p; p += 24576;
    _Float16* Wenv0bT = p; p += 24576;
    _Float16* Wenv1T  = p; p += 24576;
    _Float16* Wl1aT   = p; p += 90112;
    _Float16* Wl1bT   = p; p += 65536;
    _Float16* Wro1T   = p; p += 90112;
    float* env    = (float*)p;
    float* featN0 = env + (size_t)NNODES * 288;
    char* after = (char*)(featN0 + (size_t)NNODES * 288);
    size_t need_slow = (size_t)(after - (char*)d_ws);
    if (ws_size < need_slow) return;
    _Float16* lat1h = (_Float16*)after;                       // NE*256 f16
    _Float16* w0h   = lat1h + (size_t)NE * 256;               // NE*96 f16
    size_t need_fast = need_slow + (size_t)NE * (256 + 96) * sizeof(_Float16);
    bool fast = (ws_size >= need_fast);
    if (!fast) { lat1h = nullptr; w0h = nullptr; }

    const int ENV_N = NNODES * 288;
    k_packfin<<<3072, 256, 0, stream>>>(Wfinlat, Bfin);
    k_packf<<<160, 256, 0, stream>>>(W2a, W2aT, 136, 5, 16, 256, 0);
    k_packf<<<256, 256, 0, stream>>>(W2b, W2bT, 256, 8, 16, 256, 0);
    k_packf<<<96, 256, 0, stream>>>(Wenv0, Wenv0aT, 256, 8, 6, 192, 0);
    k_packf<<<96, 256, 0, stream>>>(Wenv0, Wenv0bT, 256, 8, 6, 192, 96);
    k_packf<<<96, 256, 0, stream>>>(Wenv1, Wenv1T, 256, 8, 6, 96, 0);
    k_packf<<<352, 256, 0, stream>>>(Wl1a, Wl1aT, 352, 11, 16, 256, 0);
    k_packf<<<256, 256, 0, stream>>>(Wl1b, Wl1bT, 256, 8, 16, 256, 0);
    k_packf<<<352, 256, 0, stream>>>(Wro1, Wro1T, 352, 11, 16, 256, 0);

    k_zero<<<(ENV_N + 255) / 256, 256, 0, stream>>>(env, ENV_N);
    k1_lat_scatter0<<<NBLK, 256, 0, stream>>>(node_inv, edge_inv, edge_len, edge_attr,
                                              eidx, W2aT, W2bT, Wenv0bT, env);
    k_node<<<NNODES, 288, 0, stream>>>(env, node_inv, Wenvlin, Wprod, Wfeat, featN0);
    k_zero<<<(ENV_N + 255) / 256, 256, 0, stream>>>(env, ENV_N);
    k3_update_scatter1<<<NBLK, 256, 0, stream>>>(node_inv, edge_inv, edge_len, edge_attr,
                                                 eidx, W2aT, W2bT, Wl1aT, Wl1bT, Wenv1T,
                                                 Wenv0aT, featN0, env, lat1h, w0h);
    k_node<<<NNODES, 288, 0, stream>>>(env, node_inv, Wenvlin + 3072, Wprod + 6144,
                                       Wfeat + 3072, env);  // in-place: env1 -> featN1
    if (fast) {
        k5_fast<<<NE / FEB, 256, 0, stream>>>(edge_attr, eidx, lat1h, w0h, Bfin, Wro1T,
                                              Wro2, env, out);
    } else {
        k5_final<<<NBLK, 256, 0, stream>>>(node_inv, edge_inv, edge_len, edge_attr, eidx,
                                           W2aT, W2bT, Wenv0aT, Wl1aT, Wl1bT, Bfin, Wro1T,
                                           Wro2, featN0, env, out);
    }
}